// Round 6
// baseline (674.665 us; speedup 1.0000x reference)
//
#include <hip/hip_runtime.h>

#define N_TOK 49152
#define PER_E 155648      // 19 stages * 8192 bf16 elems per expert
#define NSTAGE 19

// d_out float offsets
#define TRAJ_OFF 0
#define SCORE_OFF 5898240
#define AUX_OFF  5947392
#define PROB_OFF 5947393

// expert LDS element offsets (u16)
#define RING_OFF 0        // 3 slots x 8192
#define H1_OFF   24576    // 4 waves x 8192 : frag i @ w*8192 + i*512 + lane*8
#define H2_OFF   57344    // 4 waves x 4096 : frag i @ w*4096 + i*512 + lane*8

typedef __attribute__((ext_vector_type(8))) short short8v;
typedef __attribute__((ext_vector_type(4))) float f32x4;
typedef __attribute__((ext_vector_type(16))) float f32x16;
typedef __attribute__((ext_vector_type(4))) unsigned short u16x4;

typedef __attribute__((address_space(3))) unsigned char lds_byte;
typedef __attribute__((address_space(1))) const unsigned char gl_byte;

__device__ __forceinline__ unsigned short f2bf(float f) {
  unsigned int u = __float_as_uint(f);
  u = (u + 0x7FFFu + ((u >> 16) & 1u)) >> 16;
  return (unsigned short)u;
}
__device__ __forceinline__ float bf2f(unsigned short h) {
  return __uint_as_float(((unsigned int)h) << 16);
}
__device__ __forceinline__ float geluf(float v) {
  return 0.5f * v * (1.0f + erff(v * 0.70710678118654752f));
}

// ---------------- weight prep: fp32 -> bf16, A-fragment stages for 32x32x16 ----------------
// blob per expert = 19 stages x 8192 elems (16KB); stage = 16 frags of 512; elem = f*512 + l*8 + j
// A-frag: unit(row) = u*32 + (l&31); linear layers: k = ks*16 + (l>>5)*8 + j
// perm layers (input = previous MFMA output): k = 32*(ks>>1) + 16*(ks&1) + 4*(l>>5) + (j&3) + 8*(j>>2)
// physical stage order (consumption order):
//   0-1 sW1 | 2 sW2(perm) | 3-6 tW1 | 7-10 tW2 t=0..3 (units 0-127, perm)
//   11-12 tW3 t=0..1 (K 0-127, perm) | 13-16 tW2 t=4..7 (units 128-255, perm) | 17-18 tW3 t=2..3 (perm)
__global__ __launch_bounds__(256) void prep_weights(
    const float* __restrict__ tW1, const float* __restrict__ tW2, const float* __restrict__ tW3,
    const float* __restrict__ sW1, const float* __restrict__ sW2,
    unsigned short* __restrict__ blob)
{
  int id = blockIdx.x * 256 + threadIdx.x;
  if (id >= 6 * PER_E) return;
  int e = id / PER_E;
  int r = id - e * PER_E;
  int p = r >> 13;
  int q = r & 8191;
  int f = q >> 9;
  int l = (q >> 3) & 63;
  int j = q & 7;
  int hi = l >> 5, cc = l & 31;
  const float* src; int N, ks, u; bool perm;
  if (p < 2)       { src = sW1 + e * 16384; N = 128; ks = p * 4 + (f >> 2); u = f & 3; perm = false; }
  else if (p == 2) { src = sW2 + e * 8192;  N = 64;  ks = f >> 1;           u = f & 1; perm = true;  }
  else if (p < 7)  { int t = p - 3; src = tW1 + e * 32768; N = 256;
                     ks = (t & 1) * 4 + (f >> 2); u = (f & 3) + (t >> 1) * 4; perm = false; }
  else if (p < 11) { int t = p - 7; src = tW2 + e * 65536; N = 256;
                     ks = t * 4 + (f >> 2); u = f & 3; perm = true; }
  else if (p < 13) { int t = p - 11; src = tW3 + e * 30720; N = 120;
                     ks = t * 4 + (f >> 2); u = f & 3; perm = true; }
  else if (p < 17) { int t = p - 13 + 4; src = tW2 + e * 65536; N = 256;
                     ks = (t & 3) * 4 + (f >> 2); u = (f & 3) + 4; perm = true; }
  else             { int t = p - 17 + 2; src = tW3 + e * 30720; N = 120;
                     ks = t * 4 + (f >> 2); u = f & 3; perm = true; }
  int k = perm ? (32 * (ks >> 1) + 16 * (ks & 1) + 4 * hi + (j & 3) + 8 * (j >> 2))
               : (ks * 16 + hi * 8 + j);
  int col = u * 32 + cc;
  blob[id] = f2bf(col < N ? src[k * N + col] : 0.0f);
}

// ---------------- fused fp32 router (unchanged, correctness-proven) ----------------
__global__ __launch_bounds__(256) void router_kernel(
    const float* __restrict__ x,
    const float* __restrict__ rW1, const float* __restrict__ rb1,
    const float* __restrict__ rW2, const float* __restrict__ rb2,
    const float* __restrict__ rW3, const float* __restrict__ rb3,
    float* __restrict__ probs_out,
    int* __restrict__ pairTok, float* __restrict__ pairW, int* __restrict__ pairIdx,
    int* __restrict__ cnt, float* __restrict__ probsum)
{
  __shared__ float xs[32][128];
  __shared__ float h1[32][256];
  __shared__ float h2[32][132];
  __shared__ float lg[32][8];
  __shared__ float psum[8];
  __shared__ int lcnt[8], gbase[8];

  int tid = threadIdx.x;
  int tok0 = blockIdx.x * 32;

  for (int i = tid; i < 32 * 32; i += 256) {
    int row = i >> 5, c4 = i & 31;
    *(f32x4*)&xs[row][c4 * 4] = *(const f32x4*)(x + (size_t)(tok0 + row) * 128 + c4 * 4);
  }
  if (tid < 8) { psum[tid] = 0.f; lcnt[tid] = 0; }
  __syncthreads();

  {
    int u0 = (tid & 63) * 4;
    int t0 = (tid >> 6) * 8;
    float a[8][4];
    #pragma unroll
    for (int t = 0; t < 8; ++t)
      #pragma unroll
      for (int u = 0; u < 4; ++u) a[t][u] = 0.f;
    for (int db = 0; db < 32; ++db) {
      int d = db * 4;
      f32x4 wv[4];
      #pragma unroll
      for (int dd = 0; dd < 4; ++dd) wv[dd] = *(const f32x4*)(rW1 + (size_t)(d + dd) * 256 + u0);
      #pragma unroll
      for (int tt = 0; tt < 8; ++tt) {
        f32x4 xv = *(const f32x4*)&xs[t0 + tt][d];
        #pragma unroll
        for (int dd = 0; dd < 4; ++dd)
          #pragma unroll
          for (int uu = 0; uu < 4; ++uu) a[tt][uu] += xv[dd] * wv[dd][uu];
      }
    }
    f32x4 bv = *(const f32x4*)(rb1 + u0);
    #pragma unroll
    for (int tt = 0; tt < 8; ++tt) {
      f32x4 o;
      #pragma unroll
      for (int uu = 0; uu < 4; ++uu) o[uu] = geluf(a[tt][uu] + bv[uu]);
      *(f32x4*)&h1[t0 + tt][u0] = o;
    }
  }
  __syncthreads();

  {
    int u0 = (tid & 31) * 4;
    int t0 = (tid >> 5) * 4;
    float a[4][4];
    #pragma unroll
    for (int t = 0; t < 4; ++t)
      #pragma unroll
      for (int u = 0; u < 4; ++u) a[t][u] = 0.f;
    for (int db = 0; db < 64; ++db) {
      int d = db * 4;
      f32x4 wv[4];
      #pragma unroll
      for (int dd = 0; dd < 4; ++dd) wv[dd] = *(const f32x4*)(rW2 + (size_t)(d + dd) * 128 + u0);
      #pragma unroll
      for (int tt = 0; tt < 4; ++tt) {
        f32x4 xv = *(const f32x4*)&h1[t0 + tt][d];
        #pragma unroll
        for (int dd = 0; dd < 4; ++dd)
          #pragma unroll
          for (int uu = 0; uu < 4; ++uu) a[tt][uu] += xv[dd] * wv[dd][uu];
      }
    }
    f32x4 bv = *(const f32x4*)(rb2 + u0);
    #pragma unroll
    for (int tt = 0; tt < 4; ++tt) {
      f32x4 o;
      #pragma unroll
      for (int uu = 0; uu < 4; ++uu) o[uu] = geluf(a[tt][uu] + bv[uu]);
      *(f32x4*)&h2[t0 + tt][u0] = o;
    }
  }
  __syncthreads();

  if (tid < 192) {
    int t = tid / 6, e = tid - t * 6;
    float s = rb3[e];
    for (int d = 0; d < 128; ++d) s += h2[t][d] * rW3[d * 6 + e];
    lg[t][e] = s;
  }
  __syncthreads();

  int i1 = 0, i2 = 0, lp1 = 0, lp2 = 0;
  float w1 = 0.f, w2 = 0.f;
  int myTok = tok0 + tid;
  if (tid < 32) {
    float l0[6];
    #pragma unroll
    for (int e = 0; e < 6; ++e) l0[e] = lg[tid][e];
    float m = l0[0];
    #pragma unroll
    for (int e = 1; e < 6; ++e) m = fmaxf(m, l0[e]);
    float pe[6]; float ssum = 0.f;
    #pragma unroll
    for (int e = 0; e < 6; ++e) { pe[e] = expf(l0[e] - m); ssum += pe[e]; }
    float inv = 1.f / ssum;
    #pragma unroll
    for (int e = 0; e < 6; ++e) {
      float pr = pe[e] * inv;
      probs_out[(size_t)myTok * 6 + e] = pr;
      atomicAdd(&psum[e], pr);
    }
    float v1 = l0[0]; i1 = 0; float v2 = -1e30f; i2 = -1;
    #pragma unroll
    for (int e = 1; e < 6; ++e) {
      float v = l0[e];
      if (v > v1) { v2 = v1; i2 = i1; v1 = v; i1 = e; }
      else if (v > v2) { v2 = v; i2 = e; }
    }
    float e2 = expf(v2 - v1);
    float denom = 1.f / (1.f + e2);
    w1 = denom; w2 = e2 * denom;
    lp1 = atomicAdd(&lcnt[i1], 1);
    lp2 = atomicAdd(&lcnt[i2], 1);
  }
  __syncthreads();
  if (tid < 6) gbase[tid] = atomicAdd(&cnt[tid], lcnt[tid]);
  __syncthreads();
  if (tid < 32) {
    int g1 = gbase[i1] + lp1, g2 = gbase[i2] + lp2;
    pairTok[i1 * N_TOK + g1] = myTok; pairW[i1 * N_TOK + g1] = w1;
    pairTok[i2 * N_TOK + g2] = myTok; pairW[i2 * N_TOK + g2] = w2;
    pairIdx[2 * myTok]     = i1 * N_TOK + g1;
    pairIdx[2 * myTok + 1] = i2 * N_TOK + g2;
  }
  if (tid < 6) atomicAdd(&probsum[tid], psum[tid]);
}

// ---------------- aux loss + csum ----------------
__global__ void aux_kernel(const float* __restrict__ probsum, const int* __restrict__ cnt,
                           int* __restrict__ csum, float* __restrict__ auxout)
{
  if (threadIdx.x == 0 && blockIdx.x == 0) {
    int s = 0;
    for (int e = 0; e < 6; ++e) { csum[e] = s; s += cnt[e]; }
    float ent = 0.f, l2 = 0.f;
    for (int e = 0; e < 6; ++e) {
      float avg = probsum[e] / (float)N_TOK;
      ent -= avg * logf(avg + 1e-8f);
      float d = avg - (1.0f / 6.0f);
      l2 += d * d;
    }
    l2 *= (1.0f / 6.0f);
    auxout[0] = -ent * 0.01f + 0.01f * l2;
  }
}

// ---------------- expert kernel ----------------
__device__ __forceinline__ f32x16 MM(short8v a, short8v b, f32x16 c) {
  return __builtin_amdgcn_mfma_f32_32x32x16_bf16(a, b, c, 0, 0, 0);
}

// acc (one 32-unit block) + bias -> gelu -> two B-frags for the next layer (perm-absorbed)
__device__ __forceinline__ void cvt_frags(const f32x16& a, const float* __restrict__ bp,
                                          short8v& f0, short8v& f1) {
  #pragma unroll
  for (int m = 0; m < 8; ++m) {
    f0[m] = (short)f2bf(geluf(a[m] + bp[(m & 3) + 8 * (m >> 2)]));
    int r = 8 + m;
    f1[m] = (short)f2bf(geluf(a[r] + bp[(r & 3) + 8 * (r >> 2)]));
  }
}

#define STAGE(s) do { \
    const unsigned short* gsrc_ = eblob + (s) * 8192 + w * 2048 + lane * 8; \
    unsigned short* ldst_ = &wlds[((s) % 3) * 8192 + w * 2048]; \
    _Pragma("unroll") \
    for (int i_ = 0; i_ < 4; ++i_) \
      __builtin_amdgcn_global_load_lds((gl_byte*)(gsrc_ + i_ * 512), (lds_byte*)(ldst_ + i_ * 512), 16, 0, 0); \
  } while (0)

#define PIPE(s, nw) do { \
    if ((s) + 2 < NSTAGE) STAGE((s) + 2); \
    asm volatile("s_waitcnt vmcnt(" #nw ")" ::: "memory"); \
    __builtin_amdgcn_s_barrier(); \
  } while (0)

#define FRAG(s, f) (*(const short8v*)(&wlds[((s) % 3) * 8192 + (f) * 512 + lane * 8]))

template<int OUTMODE>   // 0 = scratch pair partials, 1 = atomicAdd into d_out
__global__ __launch_bounds__(256) void expert_kernel(
    const float* __restrict__ x,
    const unsigned short* __restrict__ blob,
    const float* __restrict__ tb1, const float* __restrict__ tb2, const float* __restrict__ tb3,
    const float* __restrict__ sb1, const float* __restrict__ sb2,
    const float* __restrict__ sW3, const float* __restrict__ sb3,
    const int* __restrict__ pairTok, const float* __restrict__ pairW,
    const int* __restrict__ cnt, const int* __restrict__ csum,
    float* __restrict__ traj_out, float* __restrict__ score_out,
    unsigned short* __restrict__ trajP, float* __restrict__ scoreP)
{
  int e = blockIdx.y;
  int base = blockIdx.x * 128;
  int count = cnt[e];
  if (base >= count) return;

  __shared__ __align__(16) unsigned short wlds[73728];   // 144KB: 3x16KB ring + 64KB H1 + 32KB H2half

  int tid = threadIdx.x;
  int lane = tid & 63;
  int w = tid >> 6;            // 4 waves
  int c = lane & 31;           // token column
  int hi = lane >> 5;
  const unsigned short* eblob = blob + (size_t)e * PER_E;
  int slotbase = csum[e] + base;
  int myrow = w * 32 + c;
  bool valid = (base + myrow < count);
  int pidx = e * N_TOK + base + (valid ? myrow : 0);
  int tok = pairTok[pidx];
  float gw = valid ? pairW[pidx] : 0.f;

  unsigned short* h1w = wlds + H1_OFF + w * 8192;
  unsigned short* h2w = wlds + H2_OFF + w * 4096;

  STAGE(0);
  STAGE(1);

  // gather X -> bf16 B-frags (token col = lane&31, k = ks*16 + hi*8 + j)
  short8v xf[8];
  {
    const float* px = x + (size_t)tok * 128 + hi * 8;
    #pragma unroll
    for (int ks = 0; ks < 8; ++ks) {
      f32x4 lo = *(const f32x4*)(px + ks * 16);
      f32x4 hv = *(const f32x4*)(px + ks * 16 + 4);
      short8v v;
      #pragma unroll
      for (int j = 0; j < 4; ++j) { v[j] = (short)f2bf(lo[j]); v[4 + j] = (short)f2bf(hv[j]); }
      xf[ks] = v;
    }
  }

  short8v sB[8];

  // ---- S1: sW1 @ X (stages 0-1) ----
  {
    f32x16 sacc[4] = {};
    PIPE(0, 8);
    #pragma unroll
    for (int ksl = 0; ksl < 4; ++ksl)
      #pragma unroll
      for (int u = 0; u < 4; ++u)
        sacc[u] = MM(FRAG(0, ksl * 4 + u), xf[ksl], sacc[u]);
    PIPE(1, 8);
    #pragma unroll
    for (int ksl = 0; ksl < 4; ++ksl)
      #pragma unroll
      for (int u = 0; u < 4; ++u)
        sacc[u] = MM(FRAG(1, ksl * 4 + u), xf[4 + ksl], sacc[u]);
    const float* bp = sb1 + e * 128 + 4 * hi;
    #pragma unroll
    for (int u = 0; u < 4; ++u)
      cvt_frags(sacc[u], bp + u * 32, sB[2 * u], sB[2 * u + 1]);
  }

  // ---- S2: sW2 @ SH1 (stage 2) -> score ----
  {
    f32x16 q0 = {}, q1 = {};
    PIPE(2, 8);
    #pragma unroll
    for (int ksl = 0; ksl < 8; ++ksl) {
      q0 = MM(FRAG(2, ksl * 2 + 0), sB[ksl], q0);
      q1 = MM(FRAG(2, ksl * 2 + 1), sB[ksl], q1);
    }
    const float* b2p = sb2 + e * 64 + 4 * hi;
    const float* w3p = sW3 + e * 64 + 4 * hi;
    float p = 0.f;
    #pragma unroll
    for (int r = 0; r < 16; ++r) {
      int o = (r & 3) + 8 * (r >> 2);
      p += geluf(q0[r] + b2p[o]) * w3p[o];
      p += geluf(q1[r] + b2p[32 + o]) * w3p[32 + o];
    }
    p += __shfl_xor(p, 32);
    if (hi == 0 && valid) {
      float v = gw * (p + sb3[e]);
      if (OUTMODE == 0) scoreP[slotbase + myrow] = v;
      else atomicAdd(&score_out[tok], v);
    }
  }

  // ---- T1: tW1 @ X (stages 3-6) -> H1 frags to per-wave LDS ----
  {
    const float* bp = tb1 + e * 256 + 4 * hi;
    f32x16 tacc[4] = {};
    PIPE(3, 8);
    #pragma unroll
    for (int ksl = 0; ksl < 4; ++ksl)
      #pragma unroll
      for (int u = 0; u < 4; ++u)
        tacc[u] = MM(FRAG(3, ksl * 4 + u), xf[ksl], tacc[u]);
    PIPE(4, 8);
    #pragma unroll
    for (int ksl = 0; ksl < 4; ++ksl)
      #pragma unroll
      for (int u = 0; u < 4; ++u)
        tacc[u] = MM(FRAG(4, ksl * 4 + u), xf[4 + ksl], tacc[u]);
    #pragma unroll
    for (int u = 0; u < 4; ++u) {
      short8v f0, f1;
      cvt_frags(tacc[u], bp + u * 32, f0, f1);
      *(short8v*)&h1w[(2 * u) * 512 + lane * 8] = f0;
      *(short8v*)&h1w[(2 * u + 1) * 512 + lane * 8] = f1;
    }

    f32x16 tacc2[4] = {};
    PIPE(5, 8);
    #pragma unroll
    for (int ksl = 0; ksl < 4; ++ksl)
      #pragma unroll
      for (int u = 0; u < 4; ++u)
        tacc2[u] = MM(FRAG(5, ksl * 4 + u), xf[ksl], tacc2[u]);
    PIPE(6, 8);
    #pragma unroll
    for (int ksl = 0; ksl < 4; ++ksl)
      #pragma unroll
      for (int u = 0; u < 4; ++u)
        tacc2[u] = MM(FRAG(6, ksl * 4 + u), xf[4 + ksl], tacc2[u]);
    #pragma unroll
    for (int u = 0; u < 4; ++u) {
      short8v f0, f1;
      cvt_frags(tacc2[u], bp + 128 + u * 32, f0, f1);
      *(short8v*)&h1w[(8 + 2 * u) * 512 + lane * 8] = f0;
      *(short8v*)&h1w[(9 + 2 * u) * 512 + lane * 8] = f1;
    }
  }

  f32x16 wacc[4] = {};   // T3 accumulators (persist stages 11-18)

  // ---- T2a: tW2 @ H1 -> out units 0-127 (stages 7-10) ----
  {
    const float* bp = tb2 + e * 256 + 4 * hi;
    f32x16 uacc[4] = {};
    #pragma unroll
    for (int p = 7; p <= 10; ++p) {
      PIPE(p, 8);
      #pragma unroll
      for (int ksl = 0; ksl < 4; ++ksl) {
        short8v hb = *(const short8v*)&h1w[((p - 7) * 4 + ksl) * 512 + lane * 8];
        #pragma unroll
        for (int u = 0; u < 4; ++u)
          uacc[u] = MM(FRAG(p, ksl * 4 + u), hb, uacc[u]);
      }
    }
    #pragma unroll
    for (int u = 0; u < 4; ++u) {
      short8v f0, f1;
      cvt_frags(uacc[u], bp + u * 32, f0, f1);
      *(short8v*)&h2w[(2 * u) * 512 + lane * 8] = f0;
      *(short8v*)&h2w[(2 * u + 1) * 512 + lane * 8] = f1;
    }
  }

  // ---- T3a: tW3 @ H2[0:128] (stages 11-12) ----
  PIPE(11, 8);
  #pragma unroll
  for (int ksl = 0; ksl < 4; ++ksl) {
    short8v hb = *(const short8v*)&h2w[ksl * 512 + lane * 8];
    #pragma unroll
    for (int u = 0; u < 4; ++u)
      wacc[u] = MM(FRAG(11, ksl * 4 + u), hb, wacc[u]);
  }
  PIPE(12, 8);
  #pragma unroll
  for (int ksl = 0; ksl < 4; ++ksl) {
    short8v hb = *(const short8v*)&h2w[(4 + ksl) * 512 + lane * 8];
    #pragma unroll
    for (int u = 0; u < 4; ++u)
      wacc[u] = MM(FRAG(12, ksl * 4 + u), hb, wacc[u]);
  }

  // ---- T2b: tW2 @ H1 -> out units 128-255 (stages 13-16) ----
  {
    const float* bp = tb2 + e * 256 + 128 + 4 * hi;
    f32x16 uacc[4] = {};
    #pragma unroll
    for (int p = 13; p <= 16; ++p) {
      PIPE(p, 8);
      #pragma unroll
      for (int ksl = 0; ksl < 4; ++ksl) {
        short8v hb = *(const short8v*)&h1w[((p - 13) * 4 + ksl) * 512 + lane * 8];
        #pragma unroll
        for (int u = 0; u < 4; ++u)
          uacc[u] = MM(FRAG(p, ksl * 4 + u), hb, uacc[u]);
      }
    }
    #pragma unroll
    for (int u = 0; u < 4; ++u) {
      short8v f0, f1;
      cvt_frags(uacc[u], bp + u * 32, f0, f1);
      *(short8v*)&h2w[(2 * u) * 512 + lane * 8] = f0;
      *(short8v*)&h2w[(2 * u + 1) * 512 + lane * 8] = f1;
    }
  }

  // ---- T3b: tW3 @ H2[128:256] (stages 17-18) ----
  PIPE(17, 4);
  #pragma unroll
  for (int ksl = 0; ksl < 4; ++ksl) {
    short8v hb = *(const short8v*)&h2w[ksl * 512 + lane * 8];
    #pragma unroll
    for (int u = 0; u < 4; ++u)
      wacc[u] = MM(FRAG(17, ksl * 4 + u), hb, wacc[u]);
  }
  PIPE(18, 0);
  #pragma unroll
  for (int ksl = 0; ksl < 4; ++ksl) {
    short8v hb = *(const short8v*)&h2w[(4 + ksl) * 512 + lane * 8];
    #pragma unroll
    for (int u = 0; u < 4; ++u)
      wacc[u] = MM(FRAG(18, ksl * 4 + u), hb, wacc[u]);
  }

  // ---- trajectory epilogue ----
  {
    const float* b3p = tb3 + e * 120;
    if (OUTMODE == 0) {
      if (valid) {
        unsigned short* dst = trajP + (size_t)(slotbase + myrow) * 120;
        #pragma unroll
        for (int u = 0; u < 4; ++u)
          #pragma unroll
          for (int m = 0; m < 8; ++m) {
            int r = 2 * m;
            int unit = u * 32 + (r & 3) + 8 * (r >> 2) + 4 * hi;
            if (u < 3 || m < 6) {
              float v0 = gw * (wacc[u][r] + b3p[unit]);
              float v1 = gw * (wacc[u][r + 1] + b3p[unit + 1]);
              *(unsigned int*)(dst + unit) = (unsigned)f2bf(v0) | ((unsigned)f2bf(v1) << 16);
            }
          }
      }
    } else {
      if (valid) {
        float* dst = traj_out + (size_t)tok * 120;
        #pragma unroll
        for (int u = 0; u < 4; ++u)
          #pragma unroll
          for (int r = 0; r < 16; ++r) {
            int unit = u * 32 + (r & 3) + 8 * (r >> 2) + 4 * hi;
            if (unit < 120) atomicAdd(&dst[unit], gw * (wacc[u][r] + b3p[unit]));
          }
      }
    }
  }
}

// ---------------- combine: sum each token's 2 pair partials ----------------
__global__ __launch_bounds__(256) void combine_kernel(
    const int* __restrict__ pairIdx, const int* __restrict__ csum,
    const unsigned short* __restrict__ trajP, const float* __restrict__ scoreP,
    float* __restrict__ traj_out, float* __restrict__ score_out)
{
  int t = blockIdx.x * 256 + threadIdx.x;
  if (t >= N_TOK) return;
  int p0 = pairIdx[2 * t], p1 = pairIdx[2 * t + 1];
  int e0 = p0 / N_TOK, e1 = p1 / N_TOK;
  size_t s0 = (size_t)csum[e0] + (p0 - e0 * N_TOK);
  size_t s1 = (size_t)csum[e1] + (p1 - e1 * N_TOK);
  const unsigned short* r0 = trajP + s0 * 120;
  const unsigned short* r1 = trajP + s1 * 120;
  float* o = traj_out + (size_t)t * 120;
  #pragma unroll 6
  for (int i = 0; i < 30; ++i) {
    u16x4 a = *(const u16x4*)(r0 + i * 4);
    u16x4 b = *(const u16x4*)(r1 + i * 4);
    f32x4 v;
    #pragma unroll
    for (int jj = 0; jj < 4; ++jj) v[jj] = bf2f(a[jj]) + bf2f(b[jj]);
    *(f32x4*)(o + i * 4) = v;
  }
  score_out[t] = scoreP[s0] + scoreP[s1];
}

extern "C" void kernel_launch(void* const* d_in, const int* in_sizes, int n_in,
                              void* d_out, int out_size, void* d_ws, size_t ws_size,
                              hipStream_t stream) {
  (void)in_sizes; (void)n_in; (void)out_size;
  const float* x   = (const float*)d_in[0];
  const float* rW1 = (const float*)d_in[1];
  const float* rb1 = (const float*)d_in[2];
  const float* rW2 = (const float*)d_in[3];
  const float* rb2 = (const float*)d_in[4];
  const float* rW3 = (const float*)d_in[5];
  const float* rb3 = (const float*)d_in[6];
  const float* tW1 = (const float*)d_in[7];
  const float* tb1 = (const float*)d_in[8];
  const float* tW2 = (const float*)d_in[9];
  const float* tb2 = (const float*)d_in[10];
  const float* tW3 = (const float*)d_in[11];
  const float* tb3 = (const float*)d_in[12];
  const float* sW1 = (const float*)d_in[13];
  const float* sb1 = (const float*)d_in[14];
  const float* sW2 = (const float*)d_in[15];
  const float* sb2 = (const float*)d_in[16];
  const float* sW3 = (const float*)d_in[17];
  const float* sb3 = (const float*)d_in[18];
  float* out = (float*)d_out;

  // workspace carve (bytes)
  char* wsb = (char*)d_ws;
  int*   cnt     = (int*)(wsb + 0);
  float* probsum = (float*)(wsb + 32);
  int*   csum    = (int*)(wsb + 64);
  int*   pairTok = (int*)(wsb + 96);
  float* pairW   = (float*)(wsb + 96 + (size_t)6 * N_TOK * 4);
  int*   pairIdx = (int*)(wsb + 96 + (size_t)12 * N_TOK * 4);
  float* scoreP  = (float*)(wsb + 96 + (size_t)14 * N_TOK * 4);
  unsigned short* blob = (unsigned short*)(wsb + 96 + (size_t)16 * N_TOK * 4);
  unsigned short* trajP = (unsigned short*)(wsb + 96 + (size_t)16 * N_TOK * 4 + (size_t)6 * PER_E * 2);
  size_t need = 96 + (size_t)16 * N_TOK * 4 + (size_t)6 * PER_E * 2 + (size_t)2 * N_TOK * 120 * 2;
  bool scratch = ws_size >= need;

  hipMemsetAsync(wsb, 0, 96, stream);
  if (!scratch) hipMemsetAsync(d_out, 0, (size_t)(N_TOK * 121) * 4, stream);

  prep_weights<<<(6 * PER_E) / 256, 256, 0, stream>>>(tW1, tW2, tW3, sW1, sW2, blob);
  router_kernel<<<N_TOK / 32, 256, 0, stream>>>(x, rW1, rb1, rW2, rb2, rW3, rb3,
                                                out + PROB_OFF, pairTok, pairW, pairIdx, cnt, probsum);
  aux_kernel<<<1, 64, 0, stream>>>(probsum, cnt, csum, out + AUX_OFF);
  if (scratch) {
    expert_kernel<0><<<dim3(N_TOK / 128, 6), 256, 0, stream>>>(
        x, blob, tb1, tb2, tb3, sb1, sb2, sW3, sb3, pairTok, pairW, cnt, csum,
        out + TRAJ_OFF, out + SCORE_OFF, trajP, scoreP);
    combine_kernel<<<N_TOK / 256, 256, 0, stream>>>(pairIdx, csum, trajP, scoreP,
                                                    out + TRAJ_OFF, out + SCORE_OFF);
  } else {
    expert_kernel<1><<<dim3(N_TOK / 128, 6), 256, 0, stream>>>(
        x, blob, tb1, tb2, tb3, sb1, sb2, sW3, sb3, pairTok, pairW, cnt, csum,
        out + TRAJ_OFF, out + SCORE_OFF, trajP, scoreP);
  }
}

// Round 7
// 579.206 us; speedup vs baseline: 1.1648x; 1.1648x over previous
//
#include <hip/hip_runtime.h>

#define N_TOK 49152
#define PER_E 155648      // 19 stages * 8192 bf16 elems per expert
#define NSTAGE 19

// d_out float offsets
#define TRAJ_OFF 0
#define SCORE_OFF 5898240
#define AUX_OFF  5947392
#define PROB_OFF 5947393

typedef __attribute__((ext_vector_type(8))) short short8v;
typedef __attribute__((ext_vector_type(4))) float f32x4;
typedef __attribute__((ext_vector_type(4))) unsigned short u16x4;

typedef __attribute__((address_space(3))) unsigned char lds_byte;
typedef __attribute__((address_space(1))) const unsigned char gl_byte;

__device__ __forceinline__ unsigned short f2bf(float f) {
  unsigned int u = __float_as_uint(f);
  u = (u + 0x7FFFu + ((u >> 16) & 1u)) >> 16;
  return (unsigned short)u;
}
__device__ __forceinline__ float bf2f(unsigned short h) {
  return __uint_as_float(((unsigned int)h) << 16);
}
__device__ __forceinline__ float geluf(float v) {
  return 0.5f * v * (1.0f + erff(v * 0.70710678118654752f));
}

// ---------------- weight prep: fp32 -> bf16, A-fragment stages for 16x16x32 ----------------
// blob per expert = 19 stages x 8192 elems (16KB); stage = 16 frags of 512; elem = f*512 + l*8 + j
// A-frag (weights as A operand): unit(row) = tile*16 + (l&15)
//   linear layers (X input):  k = ks*32 + 8*(l>>4) + j
//   perm layers (input = prev MFMA output): k = ks*32 + 16*(j>>2) + 4*(l>>4) + (j&3)
// stage map: 0-1 S1 | 2 S2(perm) | 3-6 T1 | 7-10 T2a(perm) | 11-12 T3a(perm)
//            13-16 T2b(perm) | 17-18 T3b(perm)
__global__ __launch_bounds__(256) void prep_weights(
    const float* __restrict__ tW1, const float* __restrict__ tW2, const float* __restrict__ tW3,
    const float* __restrict__ sW1, const float* __restrict__ sW2,
    unsigned short* __restrict__ blob)
{
  int id = blockIdx.x * 256 + threadIdx.x;
  if (id >= 6 * PER_E) return;
  int e = id / PER_E;
  int r = id - e * PER_E;
  int p = r >> 13;
  int q = r & 8191;
  int f = q >> 9;
  int l = (q >> 3) & 63;
  int j = q & 7;
  int hi = l >> 4, rl = l & 15;
  const float* src; int N, tile, ks; bool perm;
  if (p < 2)       { src = sW1 + e * 16384; N = 128; tile = 4 * p + (f >> 2);        ks = f & 3; perm = false; }
  else if (p == 2) { src = sW2 + e * 8192;  N = 64;  tile = f >> 2;                  ks = f & 3; perm = true;  }
  else if (p < 7)  { src = tW1 + e * 32768; N = 256; tile = 4 * (p - 3) + (f >> 2);  ks = f & 3; perm = false; }
  else if (p < 11) { src = tW2 + e * 65536; N = 256; tile = 2 * (p - 7) + (f >> 3);  ks = f & 7; perm = true;  }
  else if (p < 13) { src = tW3 + e * 30720; N = 120; tile = f >> 1;  ks = 2 * (p - 11) + (f & 1); perm = true; }
  else if (p < 17) { src = tW2 + e * 65536; N = 256; tile = 8 + 2 * (p - 13) + (f >> 3); ks = f & 7; perm = true; }
  else             { src = tW3 + e * 30720; N = 120; tile = f >> 1;  ks = 4 + 2 * (p - 17) + (f & 1); perm = true; }
  int k = ks * 32 + (perm ? (16 * (j >> 2) + 4 * hi + (j & 3)) : (8 * hi + j));
  int unit = tile * 16 + rl;
  blob[id] = f2bf(unit < N ? src[k * N + unit] : 0.0f);
}

// ---------------- fused fp32 router (unchanged, correctness-proven) ----------------
__global__ __launch_bounds__(256) void router_kernel(
    const float* __restrict__ x,
    const float* __restrict__ rW1, const float* __restrict__ rb1,
    const float* __restrict__ rW2, const float* __restrict__ rb2,
    const float* __restrict__ rW3, const float* __restrict__ rb3,
    float* __restrict__ probs_out,
    int* __restrict__ pairTok, float* __restrict__ pairW, int* __restrict__ pairIdx,
    int* __restrict__ cnt, float* __restrict__ probsum)
{
  __shared__ float xs[32][128];
  __shared__ float h1[32][256];
  __shared__ float h2[32][132];
  __shared__ float lg[32][8];
  __shared__ float psum[8];
  __shared__ int lcnt[8], gbase[8];

  int tid = threadIdx.x;
  int tok0 = blockIdx.x * 32;

  for (int i = tid; i < 32 * 32; i += 256) {
    int row = i >> 5, c4 = i & 31;
    *(f32x4*)&xs[row][c4 * 4] = *(const f32x4*)(x + (size_t)(tok0 + row) * 128 + c4 * 4);
  }
  if (tid < 8) { psum[tid] = 0.f; lcnt[tid] = 0; }
  __syncthreads();

  {
    int u0 = (tid & 63) * 4;
    int t0 = (tid >> 6) * 8;
    float a[8][4];
    #pragma unroll
    for (int t = 0; t < 8; ++t)
      #pragma unroll
      for (int u = 0; u < 4; ++u) a[t][u] = 0.f;
    for (int db = 0; db < 32; ++db) {
      int d = db * 4;
      f32x4 wv[4];
      #pragma unroll
      for (int dd = 0; dd < 4; ++dd) wv[dd] = *(const f32x4*)(rW1 + (size_t)(d + dd) * 256 + u0);
      #pragma unroll
      for (int tt = 0; tt < 8; ++tt) {
        f32x4 xv = *(const f32x4*)&xs[t0 + tt][d];
        #pragma unroll
        for (int dd = 0; dd < 4; ++dd)
          #pragma unroll
          for (int uu = 0; uu < 4; ++uu) a[tt][uu] += xv[dd] * wv[dd][uu];
      }
    }
    f32x4 bv = *(const f32x4*)(rb1 + u0);
    #pragma unroll
    for (int tt = 0; tt < 8; ++tt) {
      f32x4 o;
      #pragma unroll
      for (int uu = 0; uu < 4; ++uu) o[uu] = geluf(a[tt][uu] + bv[uu]);
      *(f32x4*)&h1[t0 + tt][u0] = o;
    }
  }
  __syncthreads();

  {
    int u0 = (tid & 31) * 4;
    int t0 = (tid >> 5) * 4;
    float a[4][4];
    #pragma unroll
    for (int t = 0; t < 4; ++t)
      #pragma unroll
      for (int u = 0; u < 4; ++u) a[t][u] = 0.f;
    for (int db = 0; db < 64; ++db) {
      int d = db * 4;
      f32x4 wv[4];
      #pragma unroll
      for (int dd = 0; dd < 4; ++dd) wv[dd] = *(const f32x4*)(rW2 + (size_t)(d + dd) * 128 + u0);
      #pragma unroll
      for (int tt = 0; tt < 4; ++tt) {
        f32x4 xv = *(const f32x4*)&h1[t0 + tt][d];
        #pragma unroll
        for (int dd = 0; dd < 4; ++dd)
          #pragma unroll
          for (int uu = 0; uu < 4; ++uu) a[tt][uu] += xv[dd] * wv[dd][uu];
      }
    }
    f32x4 bv = *(const f32x4*)(rb2 + u0);
    #pragma unroll
    for (int tt = 0; tt < 4; ++tt) {
      f32x4 o;
      #pragma unroll
      for (int uu = 0; uu < 4; ++uu) o[uu] = geluf(a[tt][uu] + bv[uu]);
      *(f32x4*)&h2[t0 + tt][u0] = o;
    }
  }
  __syncthreads();

  if (tid < 192) {
    int t = tid / 6, e = tid - t * 6;
    float s = rb3[e];
    for (int d = 0; d < 128; ++d) s += h2[t][d] * rW3[d * 6 + e];
    lg[t][e] = s;
  }
  __syncthreads();

  int i1 = 0, i2 = 0, lp1 = 0, lp2 = 0;
  float w1 = 0.f, w2 = 0.f;
  int myTok = tok0 + tid;
  if (tid < 32) {
    float l0[6];
    #pragma unroll
    for (int e = 0; e < 6; ++e) l0[e] = lg[tid][e];
    float m = l0[0];
    #pragma unroll
    for (int e = 1; e < 6; ++e) m = fmaxf(m, l0[e]);
    float pe[6]; float ssum = 0.f;
    #pragma unroll
    for (int e = 0; e < 6; ++e) { pe[e] = expf(l0[e] - m); ssum += pe[e]; }
    float inv = 1.f / ssum;
    #pragma unroll
    for (int e = 0; e < 6; ++e) {
      float pr = pe[e] * inv;
      probs_out[(size_t)myTok * 6 + e] = pr;
      atomicAdd(&psum[e], pr);
    }
    float v1 = l0[0]; i1 = 0; float v2 = -1e30f; i2 = -1;
    #pragma unroll
    for (int e = 1; e < 6; ++e) {
      float v = l0[e];
      if (v > v1) { v2 = v1; i2 = i1; v1 = v; i1 = e; }
      else if (v > v2) { v2 = v; i2 = e; }
    }
    float e2 = expf(v2 - v1);
    float denom = 1.f / (1.f + e2);
    w1 = denom; w2 = e2 * denom;
    lp1 = atomicAdd(&lcnt[i1], 1);
    lp2 = atomicAdd(&lcnt[i2], 1);
  }
  __syncthreads();
  if (tid < 6) gbase[tid] = atomicAdd(&cnt[tid], lcnt[tid]);
  __syncthreads();
  if (tid < 32) {
    int g1 = gbase[i1] + lp1, g2 = gbase[i2] + lp2;
    pairTok[i1 * N_TOK + g1] = myTok; pairW[i1 * N_TOK + g1] = w1;
    pairTok[i2 * N_TOK + g2] = myTok; pairW[i2 * N_TOK + g2] = w2;
    pairIdx[2 * myTok]     = i1 * N_TOK + g1;
    pairIdx[2 * myTok + 1] = i2 * N_TOK + g2;
  }
  if (tid < 6) atomicAdd(&probsum[tid], psum[tid]);
}

// ---------------- aux loss + csum ----------------
__global__ void aux_kernel(const float* __restrict__ probsum, const int* __restrict__ cnt,
                           int* __restrict__ csum, float* __restrict__ auxout)
{
  if (threadIdx.x == 0 && blockIdx.x == 0) {
    int s = 0;
    for (int e = 0; e < 6; ++e) { csum[e] = s; s += cnt[e]; }
    float ent = 0.f, l2 = 0.f;
    for (int e = 0; e < 6; ++e) {
      float avg = probsum[e] / (float)N_TOK;
      ent -= avg * logf(avg + 1e-8f);
      float d = avg - (1.0f / 6.0f);
      l2 += d * d;
    }
    l2 *= (1.0f / 6.0f);
    auxout[0] = -ent * 0.01f + 0.01f * l2;
  }
}

// ---------------- expert kernel ----------------
__device__ __forceinline__ f32x4 MM16(short8v a, short8v b, f32x4 c) {
  return __builtin_amdgcn_mfma_f32_16x16x32_bf16(a, b, c, 0, 0, 0);
}

// two 16-unit tiles (E = units [0,16), O = [16,32) of a 32-block) + bias(LDS) -> gelu -> next-layer B-frag
__device__ __forceinline__ void cvt16(f32x4 aE, f32x4 aO, const float* bp, int hi, short8v& fr) {
  #pragma unroll
  for (int j = 0; j < 8; ++j) {
    float v = (j < 4) ? aE[j & 3] : aO[j & 3];
    int unit = 16 * (j >> 2) + 4 * hi + (j & 3);
    fr[j] = (short)f2bf(geluf(v + bp[unit]));
  }
}

#define STAGE(s) do { \
    const unsigned short* gsrc_ = eblob + (s) * 8192 + w * 2048 + lane * 8; \
    unsigned short* ldst_ = &wlds[((s) % 3) * 8192 + w * 2048]; \
    _Pragma("unroll") \
    for (int i_ = 0; i_ < 4; ++i_) \
      __builtin_amdgcn_global_load_lds((gl_byte*)(gsrc_ + i_ * 512), (lds_byte*)(ldst_ + i_ * 512), 16, 0, 0); \
  } while (0)

// wait stage-s loads (oldest 4), barrier, THEN issue stage s+2 (slot (s-1)%3 -- free after barrier)
#define PIPE(s, nw) do { \
    asm volatile("s_waitcnt vmcnt(" #nw ")" ::: "memory"); \
    __builtin_amdgcn_sched_barrier(0); \
    __builtin_amdgcn_s_barrier(); \
    __builtin_amdgcn_sched_barrier(0); \
    if ((s) + 2 < NSTAGE) STAGE((s) + 2); \
  } while (0)

#define FRAG(s, f) (*(const short8v*)(&wlds[((s) % 3) * 8192 + (f) * 512 + lane * 8]))

template<int OUTMODE>   // 0 = scratch pair partials, 1 = atomicAdd into d_out
__global__ __launch_bounds__(256, 2) void expert_kernel(
    const float* __restrict__ x,
    const unsigned short* __restrict__ blob,
    const float* __restrict__ tb1, const float* __restrict__ tb2, const float* __restrict__ tb3,
    const float* __restrict__ sb1, const float* __restrict__ sb2,
    const float* __restrict__ sW3, const float* __restrict__ sb3,
    const int* __restrict__ pairTok, const float* __restrict__ pairW,
    const int* __restrict__ cnt, const int* __restrict__ csum,
    float* __restrict__ traj_out, float* __restrict__ score_out,
    unsigned short* __restrict__ trajP, float* __restrict__ scoreP)
{
  int e = blockIdx.y;
  int base = blockIdx.x * 128;
  int count = cnt[e];
  if (base >= count) return;

  __shared__ __align__(16) unsigned short wlds[3 * 8192];   // 48KB ring
  __shared__ float bLds[896];                               // biases (keeps VMEM out of the K-loop)
  __shared__ int   toksLds[128];
  __shared__ float gwsLds[128];

  int tid = threadIdx.x;
  int lane = tid & 63;
  int w = tid >> 6;            // 4 waves
  int col = lane & 15;
  int hi = lane >> 4;
  const unsigned short* eblob = blob + (size_t)e * PER_E;
  int slotbase = csum[e] + base;

  if (tid < 128) {
    int idx = e * N_TOK + base + ((base + tid < count) ? tid : 0);
    toksLds[tid] = pairTok[idx];
    gwsLds[tid] = (base + tid < count) ? pairW[idx] : 0.f;
  }
  // biases -> LDS: [0,128) sb1 | [128,192) sb2 | [192,256) sW3 | [256,512) tb1 | [512,768) tb2 | [768,888) tb3
  if (tid < 128) bLds[tid] = sb1[e * 128 + tid];
  if (tid < 64)  bLds[128 + tid] = sb2[e * 64 + tid];
  if (tid < 64)  bLds[192 + tid] = sW3[e * 64 + tid];
  bLds[256 + tid] = tb1[e * 256 + tid];
  bLds[512 + tid] = tb2[e * 256 + tid];
  if (tid < 120) bLds[768 + tid] = tb3[e * 120 + tid];
  __syncthreads();

  int row0 = w * 32 + col, row1 = row0 + 16;
  int tok0 = toksLds[row0], tok1 = toksLds[row1];
  bool v0 = (base + row0 < count), v1 = (base + row1 < count);
  float gw0 = gwsLds[row0], gw1 = gwsLds[row1];

  // gather X -> B-frags (token col = lane&15, k = ks*32 + hi*8 + j); fully retired before pipeline
  short8v xf[2][4];
  #pragma unroll
  for (int g = 0; g < 2; ++g) {
    const float* px = x + (size_t)(g ? tok1 : tok0) * 128 + hi * 8;
    #pragma unroll
    for (int ks = 0; ks < 4; ++ks) {
      f32x4 lo = *(const f32x4*)(px + ks * 32);
      f32x4 hv = *(const f32x4*)(px + ks * 32 + 4);
      short8v t;
      #pragma unroll
      for (int j = 0; j < 4; ++j) { t[j] = (short)f2bf(lo[j]); t[4 + j] = (short)f2bf(hv[j]); }
      xf[g][ks] = t;
    }
  }

  STAGE(0);
  STAGE(1);

  short8v sB[2][4];
  // ---- S1: sW1 @ X (stages 0-1) ----
  {
    f32x4 a[2][4] = {};
    PIPE(0, 4);
    #pragma unroll
    for (int f = 0; f < 16; ++f) {
      short8v wf = FRAG(0, f);
      a[0][f >> 2] = MM16(wf, xf[0][f & 3], a[0][f >> 2]);
      a[1][f >> 2] = MM16(wf, xf[1][f & 3], a[1][f >> 2]);
    }
    cvt16(a[0][0], a[0][1], bLds + 0,  hi, sB[0][0]);  cvt16(a[0][2], a[0][3], bLds + 32, hi, sB[0][1]);
    cvt16(a[1][0], a[1][1], bLds + 0,  hi, sB[1][0]);  cvt16(a[1][2], a[1][3], bLds + 32, hi, sB[1][1]);
    f32x4 b[2][4] = {};
    PIPE(1, 4);
    #pragma unroll
    for (int f = 0; f < 16; ++f) {
      short8v wf = FRAG(1, f);
      b[0][f >> 2] = MM16(wf, xf[0][f & 3], b[0][f >> 2]);
      b[1][f >> 2] = MM16(wf, xf[1][f & 3], b[1][f >> 2]);
    }
    cvt16(b[0][0], b[0][1], bLds + 64, hi, sB[0][2]);  cvt16(b[0][2], b[0][3], bLds + 96, hi, sB[0][3]);
    cvt16(b[1][0], b[1][1], bLds + 64, hi, sB[1][2]);  cvt16(b[1][2], b[1][3], bLds + 96, hi, sB[1][3]);
  }

  // ---- S2: sW2 @ SH1 (stage 2) -> score (held in regs, stored at end) ----
  float p0 = 0.f, p1 = 0.f;
  {
    f32x4 q[2][4] = {};
    PIPE(2, 4);
    #pragma unroll
    for (int f = 0; f < 16; ++f) {
      short8v wf = FRAG(2, f);
      q[0][f >> 2] = MM16(wf, sB[0][f & 3], q[0][f >> 2]);
      q[1][f >> 2] = MM16(wf, sB[1][f & 3], q[1][f >> 2]);
    }
    #pragma unroll
    for (int t = 0; t < 4; ++t)
      #pragma unroll
      for (int r = 0; r < 4; ++r) {
        int unit = t * 16 + 4 * hi + r;
        float bv = bLds[128 + unit], wv = bLds[192 + unit];
        p0 += geluf(q[0][t][r] + bv) * wv;
        p1 += geluf(q[1][t][r] + bv) * wv;
      }
    p0 += __shfl_xor(p0, 16); p0 += __shfl_xor(p0, 32);
    p1 += __shfl_xor(p1, 16); p1 += __shfl_xor(p1, 32);
  }

  // ---- T1: tW1 @ X (stages 3-6) -> h1B ----
  short8v h1B[2][8];
  #define T1S(t, S) { \
    f32x4 a[2][4] = {}; \
    PIPE(S, 4); \
    _Pragma("unroll") \
    for (int f = 0; f < 16; ++f) { \
      short8v wf = FRAG(S, f); \
      a[0][f >> 2] = MM16(wf, xf[0][f & 3], a[0][f >> 2]); \
      a[1][f >> 2] = MM16(wf, xf[1][f & 3], a[1][f >> 2]); \
    } \
    cvt16(a[0][0], a[0][1], bLds + 256 + (t) * 64,      hi, h1B[0][2 * (t)]); \
    cvt16(a[0][2], a[0][3], bLds + 256 + (t) * 64 + 32, hi, h1B[0][2 * (t) + 1]); \
    cvt16(a[1][0], a[1][1], bLds + 256 + (t) * 64,      hi, h1B[1][2 * (t)]); \
    cvt16(a[1][2], a[1][3], bLds + 256 + (t) * 64 + 32, hi, h1B[1][2 * (t) + 1]); \
  }
  T1S(0, 3) T1S(1, 4) T1S(2, 5) T1S(3, 6)

  // ---- T2 stage: 2 tiles x 8 k-slices -> one h2B frag ----
  short8v h2B[2][4];
  #define T2S(s, S, BOFF) { \
    f32x4 u[2][2] = {}; \
    PIPE(S, 4); \
    _Pragma("unroll") \
    for (int f = 0; f < 16; ++f) { \
      short8v wf = FRAG(S, f); \
      u[0][f >> 3] = MM16(wf, h1B[0][f & 7], u[0][f >> 3]); \
      u[1][f >> 3] = MM16(wf, h1B[1][f & 7], u[1][f >> 3]); \
    } \
    cvt16(u[0][0], u[0][1], bLds + 512 + (BOFF) + 32 * (s), hi, h2B[0][s]); \
    cvt16(u[1][0], u[1][1], bLds + 512 + (BOFF) + 32 * (s), hi, h2B[1][s]); \
  }

  f32x4 wacc[2][8] = {};
  #define T3S(s, S, NW) { \
    PIPE(S, NW); \
    _Pragma("unroll") \
    for (int f = 0; f < 16; ++f) { \
      short8v wf = FRAG(S, f); \
      wacc[0][f >> 1] = MM16(wf, h2B[0][2 * (s) + (f & 1)], wacc[0][f >> 1]); \
      wacc[1][f >> 1] = MM16(wf, h2B[1][2 * (s) + (f & 1)], wacc[1][f >> 1]); \
    } \
  }

  // T2a (7-10) -> T3a (11-12) -> T2b (13-16) -> T3b (17-18)
  T2S(0, 7, 0) T2S(1, 8, 0) T2S(2, 9, 0) T2S(3, 10, 0)
  T3S(0, 11, 4) T3S(1, 12, 4)
  T2S(0, 13, 128) T2S(1, 14, 128) T2S(2, 15, 128) T2S(3, 16, 128)
  T3S(0, 17, 4) T3S(1, 18, 0)

  // ---- epilogue: scores + trajectories ----
  if (hi == 0) {
    float sb3e = sb3[e];
    if (v0) { float v = gw0 * (p0 + sb3e);
      if (OUTMODE == 0) scoreP[slotbase + row0] = v; else atomicAdd(&score_out[tok0], v); }
    if (v1) { float v = gw1 * (p1 + sb3e);
      if (OUTMODE == 0) scoreP[slotbase + row1] = v; else atomicAdd(&score_out[tok1], v); }
  }
  #pragma unroll
  for (int g = 0; g < 2; ++g) {
    bool vv = g ? v1 : v0;
    if (!vv) continue;
    float gw = g ? gw1 : gw0;
    int row = g ? row1 : row0;
    int tk  = g ? tok1 : tok0;
    if (OUTMODE == 0) {
      unsigned short* dst = trajP + (size_t)(slotbase + row) * 120;
      #pragma unroll
      for (int t = 0; t < 8; ++t)
        #pragma unroll
        for (int r = 0; r < 4; r += 2) {
          int unit = t * 16 + 4 * hi + r;
          if (unit + 1 < 120) {
            float a0 = gw * (wacc[g][t][r] + bLds[768 + unit]);
            float a1 = gw * (wacc[g][t][r + 1] + bLds[768 + unit + 1]);
            *(unsigned int*)(dst + unit) = (unsigned)f2bf(a0) | ((unsigned)f2bf(a1) << 16);
          }
        }
    } else {
      float* dst = traj_out + (size_t)tk * 120;
      #pragma unroll
      for (int t = 0; t < 8; ++t)
        #pragma unroll
        for (int r = 0; r < 4; ++r) {
          int unit = t * 16 + 4 * hi + r;
          if (unit < 120) atomicAdd(&dst[unit], gw * (wacc[g][t][r] + bLds[768 + unit]));
        }
    }
  }
}

// ---------------- combine: sum each token's 2 pair partials ----------------
__global__ __launch_bounds__(256) void combine_kernel(
    const int* __restrict__ pairIdx, const int* __restrict__ csum,
    const unsigned short* __restrict__ trajP, const float* __restrict__ scoreP,
    float* __restrict__ traj_out, float* __restrict__ score_out)
{
  int t = blockIdx.x * 256 + threadIdx.x;
  if (t >= N_TOK) return;
  int p0 = pairIdx[2 * t], p1 = pairIdx[2 * t + 1];
  int e0 = p0 / N_TOK, e1 = p1 / N_TOK;
  size_t s0 = (size_t)csum[e0] + (p0 - e0 * N_TOK);
  size_t s1 = (size_t)csum[e1] + (p1 - e1 * N_TOK);
  const unsigned short* r0 = trajP + s0 * 120;
  const unsigned short* r1 = trajP + s1 * 120;
  float* o = traj_out + (size_t)t * 120;
  #pragma unroll 6
  for (int i = 0; i < 30; ++i) {
    u16x4 a = *(const u16x4*)(r0 + i * 4);
    u16x4 b = *(const u16x4*)(r1 + i * 4);
    f32x4 v;
    #pragma unroll
    for (int jj = 0; jj < 4; ++jj) v[jj] = bf2f(a[jj]) + bf2f(b[jj]);
    *(f32x4*)(o + i * 4) = v;
  }
  score_out[t] = scoreP[s0] + scoreP[s1];
}

extern "C" void kernel_launch(void* const* d_in, const int* in_sizes, int n_in,
                              void* d_out, int out_size, void* d_ws, size_t ws_size,
                              hipStream_t stream) {
  (void)in_sizes; (void)n_in; (void)out_size;
  const float* x   = (const float*)d_in[0];
  const float* rW1 = (const float*)d_in[1];
  const float* rb1 = (const float*)d_in[2];
  const float* rW2 = (const float*)d_in[3];
  const float* rb2 = (const float*)d_in[4];
  const float* rW3 = (const float*)d_in[5];
  const float* rb3 = (const float*)d_in[6];
  const float* tW1 = (const float*)d_in[7];
  const float* tb1 = (const float*)d_in[8];
  const float* tW2 = (const float*)d_in[9];
  const float* tb2 = (const float*)d_in[10];
  const float* tW3 = (const float*)d_in[11];
  const float* tb3 = (const float*)d_in[12];
  const float* sW1 = (const float*)d_in[13];
  const float* sb1 = (const float*)d_in[14];
  const float* sW2 = (const float*)d_in[15];
  const float* sb2 = (const float*)d_in[16];
  const float* sW3 = (const float*)d_in[17];
  const float* sb3 = (const float*)d_in[18];
  float* out = (float*)d_out;

  // workspace carve (bytes)
  char* wsb = (char*)d_ws;
  int*   cnt     = (int*)(wsb + 0);
  float* probsum = (float*)(wsb + 32);
  int*   csum    = (int*)(wsb + 64);
  int*   pairTok = (int*)(wsb + 96);
  float* pairW   = (float*)(wsb + 96 + (size_t)6 * N_TOK * 4);
  int*   pairIdx = (int*)(wsb + 96 + (size_t)12 * N_TOK * 4);
  float* scoreP  = (float*)(wsb + 96 + (size_t)14 * N_TOK * 4);
  unsigned short* blob = (unsigned short*)(wsb + 96 + (size_t)16 * N_TOK * 4);
  unsigned short* trajP = (unsigned short*)(wsb + 96 + (size_t)16 * N_TOK * 4 + (size_t)6 * PER_E * 2);
  size_t need = 96 + (size_t)16 * N_TOK * 4 + (size_t)6 * PER_E * 2 + (size_t)2 * N_TOK * 120 * 2;
  bool scratch = ws_size >= need;

  hipMemsetAsync(wsb, 0, 96, stream);
  if (!scratch) hipMemsetAsync(d_out, 0, (size_t)(N_TOK * 121) * 4, stream);

  prep_weights<<<(6 * PER_E) / 256, 256, 0, stream>>>(tW1, tW2, tW3, sW1, sW2, blob);
  router_kernel<<<N_TOK / 32, 256, 0, stream>>>(x, rW1, rb1, rW2, rb2, rW3, rb3,
                                                out + PROB_OFF, pairTok, pairW, pairIdx, cnt, probsum);
  aux_kernel<<<1, 64, 0, stream>>>(probsum, cnt, csum, out + AUX_OFF);
  if (scratch) {
    expert_kernel<0><<<dim3(N_TOK / 128, 6), 256, 0, stream>>>(
        x, blob, tb1, tb2, tb3, sb1, sb2, sW3, sb3, pairTok, pairW, cnt, csum,
        out + TRAJ_OFF, out + SCORE_OFF, trajP, scoreP);
    combine_kernel<<<N_TOK / 256, 256, 0, stream>>>(pairIdx, csum, trajP, scoreP,
                                                    out + TRAJ_OFF, out + SCORE_OFF);
  } else {
    expert_kernel<1><<<dim3(N_TOK / 128, 6), 256, 0, stream>>>(
        x, blob, tb1, tb2, tb3, sb1, sb2, sW3, sb3, pairTok, pairW, cnt, csum,
        out + TRAJ_OFF, out + SCORE_OFF, trajP, scoreP);
  }
}

// Round 8
// 386.538 us; speedup vs baseline: 1.7454x; 1.4984x over previous
//
#include <hip/hip_runtime.h>

#define N_TOK 49152
#define PER_E 155648      // 19 stages * 8192 bf16 elems per expert
#define NSTAGE 19

// d_out float offsets
#define TRAJ_OFF 0
#define SCORE_OFF 5898240
#define AUX_OFF  5947392
#define PROB_OFF 5947393

typedef __attribute__((ext_vector_type(8))) short short8v;
typedef __attribute__((ext_vector_type(4))) float f32x4;
typedef __attribute__((ext_vector_type(4))) unsigned short u16x4;

typedef __attribute__((address_space(3))) unsigned char lds_byte;
typedef __attribute__((address_space(1))) const unsigned char gl_byte;

__device__ __forceinline__ unsigned short f2bf(float f) {
  unsigned int u = __float_as_uint(f);
  u = (u + 0x7FFFu + ((u >> 16) & 1u)) >> 16;
  return (unsigned short)u;
}
__device__ __forceinline__ float bf2f(unsigned short h) {
  return __uint_as_float(((unsigned int)h) << 16);
}
__device__ __forceinline__ float geluf(float v) {
  return 0.5f * v * (1.0f + erff(v * 0.70710678118654752f));
}

// ---------------- weight prep: fp32 -> bf16, A-fragment stages for 16x16x32 ----------------
// (verified in R7: absmax 9.8e-4)
__global__ __launch_bounds__(256) void prep_weights(
    const float* __restrict__ tW1, const float* __restrict__ tW2, const float* __restrict__ tW3,
    const float* __restrict__ sW1, const float* __restrict__ sW2,
    unsigned short* __restrict__ blob)
{
  int id = blockIdx.x * 256 + threadIdx.x;
  if (id >= 6 * PER_E) return;
  int e = id / PER_E;
  int r = id - e * PER_E;
  int p = r >> 13;
  int q = r & 8191;
  int f = q >> 9;
  int l = (q >> 3) & 63;
  int j = q & 7;
  int hi = l >> 4, rl = l & 15;
  const float* src; int N, tile, ks; bool perm;
  if (p < 2)       { src = sW1 + e * 16384; N = 128; tile = 4 * p + (f >> 2);        ks = f & 3; perm = false; }
  else if (p == 2) { src = sW2 + e * 8192;  N = 64;  tile = f >> 2;                  ks = f & 3; perm = true;  }
  else if (p < 7)  { src = tW1 + e * 32768; N = 256; tile = 4 * (p - 3) + (f >> 2);  ks = f & 3; perm = false; }
  else if (p < 11) { src = tW2 + e * 65536; N = 256; tile = 2 * (p - 7) + (f >> 3);  ks = f & 7; perm = true;  }
  else if (p < 13) { src = tW3 + e * 30720; N = 120; tile = f >> 1;  ks = 2 * (p - 11) + (f & 1); perm = true; }
  else if (p < 17) { src = tW2 + e * 65536; N = 256; tile = 8 + 2 * (p - 13) + (f >> 3); ks = f & 7; perm = true; }
  else             { src = tW3 + e * 30720; N = 120; tile = f >> 1;  ks = 4 + 2 * (p - 17) + (f & 1); perm = true; }
  int k = ks * 32 + (perm ? (16 * (j >> 2) + 4 * hi + (j & 3)) : (8 * hi + j));
  int unit = tile * 16 + rl;
  blob[id] = f2bf(unit < N ? src[k * N + unit] : 0.0f);
}

// ---------------- fused fp32 router (unchanged, correctness-proven) ----------------
__global__ __launch_bounds__(256) void router_kernel(
    const float* __restrict__ x,
    const float* __restrict__ rW1, const float* __restrict__ rb1,
    const float* __restrict__ rW2, const float* __restrict__ rb2,
    const float* __restrict__ rW3, const float* __restrict__ rb3,
    float* __restrict__ probs_out,
    int* __restrict__ pairTok, float* __restrict__ pairW, int* __restrict__ pairIdx,
    int* __restrict__ cnt, float* __restrict__ probsum)
{
  __shared__ float xs[32][128];
  __shared__ float h1[32][256];
  __shared__ float h2[32][132];
  __shared__ float lg[32][8];
  __shared__ float psum[8];
  __shared__ int lcnt[8], gbase[8];

  int tid = threadIdx.x;
  int tok0 = blockIdx.x * 32;

  for (int i = tid; i < 32 * 32; i += 256) {
    int row = i >> 5, c4 = i & 31;
    *(f32x4*)&xs[row][c4 * 4] = *(const f32x4*)(x + (size_t)(tok0 + row) * 128 + c4 * 4);
  }
  if (tid < 8) { psum[tid] = 0.f; lcnt[tid] = 0; }
  __syncthreads();

  {
    int u0 = (tid & 63) * 4;
    int t0 = (tid >> 6) * 8;
    float a[8][4];
    #pragma unroll
    for (int t = 0; t < 8; ++t)
      #pragma unroll
      for (int u = 0; u < 4; ++u) a[t][u] = 0.f;
    for (int db = 0; db < 32; ++db) {
      int d = db * 4;
      f32x4 wv[4];
      #pragma unroll
      for (int dd = 0; dd < 4; ++dd) wv[dd] = *(const f32x4*)(rW1 + (size_t)(d + dd) * 256 + u0);
      #pragma unroll
      for (int tt = 0; tt < 8; ++tt) {
        f32x4 xv = *(const f32x4*)&xs[t0 + tt][d];
        #pragma unroll
        for (int dd = 0; dd < 4; ++dd)
          #pragma unroll
          for (int uu = 0; uu < 4; ++uu) a[tt][uu] += xv[dd] * wv[dd][uu];
      }
    }
    f32x4 bv = *(const f32x4*)(rb1 + u0);
    #pragma unroll
    for (int tt = 0; tt < 8; ++tt) {
      f32x4 o;
      #pragma unroll
      for (int uu = 0; uu < 4; ++uu) o[uu] = geluf(a[tt][uu] + bv[uu]);
      *(f32x4*)&h1[t0 + tt][u0] = o;
    }
  }
  __syncthreads();

  {
    int u0 = (tid & 31) * 4;
    int t0 = (tid >> 5) * 4;
    float a[4][4];
    #pragma unroll
    for (int t = 0; t < 4; ++t)
      #pragma unroll
      for (int u = 0; u < 4; ++u) a[t][u] = 0.f;
    for (int db = 0; db < 64; ++db) {
      int d = db * 4;
      f32x4 wv[4];
      #pragma unroll
      for (int dd = 0; dd < 4; ++dd) wv[dd] = *(const f32x4*)(rW2 + (size_t)(d + dd) * 128 + u0);
      #pragma unroll
      for (int tt = 0; tt < 4; ++tt) {
        f32x4 xv = *(const f32x4*)&h1[t0 + tt][d];
        #pragma unroll
        for (int dd = 0; dd < 4; ++dd)
          #pragma unroll
          for (int uu = 0; uu < 4; ++uu) a[tt][uu] += xv[dd] * wv[dd][uu];
      }
    }
    f32x4 bv = *(const f32x4*)(rb2 + u0);
    #pragma unroll
    for (int tt = 0; tt < 4; ++tt) {
      f32x4 o;
      #pragma unroll
      for (int uu = 0; uu < 4; ++uu) o[uu] = geluf(a[tt][uu] + bv[uu]);
      *(f32x4*)&h2[t0 + tt][u0] = o;
    }
  }
  __syncthreads();

  if (tid < 192) {
    int t = tid / 6, e = tid - t * 6;
    float s = rb3[e];
    for (int d = 0; d < 128; ++d) s += h2[t][d] * rW3[d * 6 + e];
    lg[t][e] = s;
  }
  __syncthreads();

  int i1 = 0, i2 = 0, lp1 = 0, lp2 = 0;
  float w1 = 0.f, w2 = 0.f;
  int myTok = tok0 + tid;
  if (tid < 32) {
    float l0[6];
    #pragma unroll
    for (int e = 0; e < 6; ++e) l0[e] = lg[tid][e];
    float m = l0[0];
    #pragma unroll
    for (int e = 1; e < 6; ++e) m = fmaxf(m, l0[e]);
    float pe[6]; float ssum = 0.f;
    #pragma unroll
    for (int e = 0; e < 6; ++e) { pe[e] = expf(l0[e] - m); ssum += pe[e]; }
    float inv = 1.f / ssum;
    #pragma unroll
    for (int e = 0; e < 6; ++e) {
      float pr = pe[e] * inv;
      probs_out[(size_t)myTok * 6 + e] = pr;
      atomicAdd(&psum[e], pr);
    }
    float v1 = l0[0]; i1 = 0; float v2 = -1e30f; i2 = -1;
    #pragma unroll
    for (int e = 1; e < 6; ++e) {
      float v = l0[e];
      if (v > v1) { v2 = v1; i2 = i1; v1 = v; i1 = e; }
      else if (v > v2) { v2 = v; i2 = e; }
    }
    float e2 = expf(v2 - v1);
    float denom = 1.f / (1.f + e2);
    w1 = denom; w2 = e2 * denom;
    lp1 = atomicAdd(&lcnt[i1], 1);
    lp2 = atomicAdd(&lcnt[i2], 1);
  }
  __syncthreads();
  if (tid < 6) gbase[tid] = atomicAdd(&cnt[tid], lcnt[tid]);
  __syncthreads();
  if (tid < 32) {
    int g1 = gbase[i1] + lp1, g2 = gbase[i2] + lp2;
    pairTok[i1 * N_TOK + g1] = myTok; pairW[i1 * N_TOK + g1] = w1;
    pairTok[i2 * N_TOK + g2] = myTok; pairW[i2 * N_TOK + g2] = w2;
    pairIdx[2 * myTok]     = i1 * N_TOK + g1;
    pairIdx[2 * myTok + 1] = i2 * N_TOK + g2;
  }
  if (tid < 6) atomicAdd(&probsum[tid], psum[tid]);
}

// ---------------- aux loss + csum ----------------
__global__ void aux_kernel(const float* __restrict__ probsum, const int* __restrict__ cnt,
                           int* __restrict__ csum, float* __restrict__ auxout)
{
  if (threadIdx.x == 0 && blockIdx.x == 0) {
    int s = 0;
    for (int e = 0; e < 6; ++e) { csum[e] = s; s += cnt[e]; }
    float ent = 0.f, l2 = 0.f;
    for (int e = 0; e < 6; ++e) {
      float avg = probsum[e] / (float)N_TOK;
      ent -= avg * logf(avg + 1e-8f);
      float d = avg - (1.0f / 6.0f);
      l2 += d * d;
    }
    l2 *= (1.0f / 6.0f);
    auxout[0] = -ent * 0.01f + 0.01f * l2;
  }
}

// ---------------- expert kernel ----------------
__device__ __forceinline__ f32x4 MM16(short8v a, short8v b, f32x4 c) {
  return __builtin_amdgcn_mfma_f32_16x16x32_bf16(a, b, c, 0, 0, 0);
}

// two 16-unit tiles + bias(LDS) -> gelu -> next-layer B-frag (perm-absorbed)
__device__ __forceinline__ void cvt16(f32x4 aE, f32x4 aO, const float* bp, int hi, short8v& fr) {
  #pragma unroll
  for (int j = 0; j < 8; ++j) {
    float v = (j < 4) ? aE[j & 3] : aO[j & 3];
    int unit = 16 * (j >> 2) + 4 * hi + (j & 3);
    fr[j] = (short)f2bf(geluf(v + bp[unit]));
  }
}

#define STAGE(s) do { \
    const unsigned short* gsrc_ = eblob + (s) * 8192 + w * 2048 + lane * 8; \
    unsigned short* ldst_ = &wlds[((s) % 3) * 8192 + w * 2048]; \
    _Pragma("unroll") \
    for (int i_ = 0; i_ < 4; ++i_) \
      __builtin_amdgcn_global_load_lds((gl_byte*)(gsrc_ + i_ * 512), (lds_byte*)(ldst_ + i_ * 512), 16, 0, 0); \
  } while (0)

// wait stage-s loads (4 retired, 4 of s+1 in flight), barrier, THEN issue stage s+2
#define PIPE(s, nw) do { \
    asm volatile("s_waitcnt vmcnt(" #nw ")" ::: "memory"); \
    __builtin_amdgcn_sched_barrier(0); \
    __builtin_amdgcn_s_barrier(); \
    __builtin_amdgcn_sched_barrier(0); \
    if ((s) + 2 < NSTAGE) STAGE((s) + 2); \
  } while (0)

#define FRAG(s, f) (*(const short8v*)(&wlds[((s) % 3) * 8192 + (f) * 512 + lane * 8]))

template<int OUTMODE>   // 0 = scratch pair partials, 1 = atomicAdd into d_out
__global__ __launch_bounds__(256) void expert_kernel(
    const float* __restrict__ x,
    const unsigned short* __restrict__ blob,
    const float* __restrict__ tb1, const float* __restrict__ tb2, const float* __restrict__ tb3,
    const float* __restrict__ sb1, const float* __restrict__ sb2,
    const float* __restrict__ sW3, const float* __restrict__ sb3,
    const int* __restrict__ pairTok, const float* __restrict__ pairW,
    const int* __restrict__ cnt, const int* __restrict__ csum,
    float* __restrict__ traj_out, float* __restrict__ score_out,
    unsigned short* __restrict__ trajP, float* __restrict__ scoreP)
{
  int e = blockIdx.y;
  int base = blockIdx.x * 64;
  int count = cnt[e];
  if (base >= count) return;

  __shared__ __align__(16) unsigned short wlds[3 * 8192];   // 48KB ring
  __shared__ float bLds[896];
  __shared__ int   toksLds[64];
  __shared__ float gwsLds[64];

  int tid = threadIdx.x;
  int lane = tid & 63;
  int w = tid >> 6;            // 4 waves
  int col = lane & 15;
  int hi = lane >> 4;
  const unsigned short* eblob = blob + (size_t)e * PER_E;
  int slotbase = csum[e] + base;

  if (tid < 64) {
    int idx = e * N_TOK + base + ((base + tid < count) ? tid : 0);
    toksLds[tid] = pairTok[idx];
    gwsLds[tid] = (base + tid < count) ? pairW[idx] : 0.f;
  }
  // biases -> LDS: [0,128) sb1 | [128,192) sb2 | [192,256) sW3 | [256,512) tb1 | [512,768) tb2 | [768,888) tb3
  if (tid < 128) bLds[tid] = sb1[e * 128 + tid];
  if (tid < 64)  bLds[128 + tid] = sb2[e * 64 + tid];
  if (tid < 64)  bLds[192 + tid] = sW3[e * 64 + tid];
  bLds[256 + tid] = tb1[e * 256 + tid];
  bLds[512 + tid] = tb2[e * 256 + tid];
  if (tid < 120) bLds[768 + tid] = tb3[e * 120 + tid];
  __syncthreads();

  int row = w * 16 + col;
  int tok = toksLds[row];
  bool valid = (base + row < count);
  float gw = gwsLds[row];

  // gather X -> B-frags (token col = lane&15, k = ks*32 + hi*8 + j); retired before pipeline
  short8v xf[4];
  {
    const float* px = x + (size_t)tok * 128 + hi * 8;
    #pragma unroll
    for (int ks = 0; ks < 4; ++ks) {
      f32x4 lo = *(const f32x4*)(px + ks * 32);
      f32x4 hv = *(const f32x4*)(px + ks * 32 + 4);
      short8v t;
      #pragma unroll
      for (int j = 0; j < 4; ++j) { t[j] = (short)f2bf(lo[j]); t[4 + j] = (short)f2bf(hv[j]); }
      xf[ks] = t;
    }
  }

  STAGE(0);
  STAGE(1);

  short8v sB[4];
  // ---- S1: sW1 @ X (stages 0-1) ----
  {
    f32x4 a[4] = {};
    PIPE(0, 4);
    #pragma unroll
    for (int f = 0; f < 16; ++f)
      a[f >> 2] = MM16(FRAG(0, f), xf[f & 3], a[f >> 2]);
    cvt16(a[0], a[1], bLds + 0,  hi, sB[0]);  cvt16(a[2], a[3], bLds + 32, hi, sB[1]);
    f32x4 b[4] = {};
    PIPE(1, 4);
    #pragma unroll
    for (int f = 0; f < 16; ++f)
      b[f >> 2] = MM16(FRAG(1, f), xf[f & 3], b[f >> 2]);
    cvt16(b[0], b[1], bLds + 64, hi, sB[2]);  cvt16(b[2], b[3], bLds + 96, hi, sB[3]);
  }

  // ---- S2: sW2 @ SH1 (stage 2) -> score (held in regs) ----
  float p0 = 0.f;
  {
    f32x4 q[4] = {};
    PIPE(2, 4);
    #pragma unroll
    for (int f = 0; f < 16; ++f)
      q[f >> 2] = MM16(FRAG(2, f), sB[f & 3], q[f >> 2]);
    #pragma unroll
    for (int t = 0; t < 4; ++t)
      #pragma unroll
      for (int r = 0; r < 4; ++r) {
        int unit = t * 16 + 4 * hi + r;
        p0 += geluf(q[t][r] + bLds[128 + unit]) * bLds[192 + unit];
      }
    p0 += __shfl_xor(p0, 16); p0 += __shfl_xor(p0, 32);
  }

  // ---- T1: tW1 @ X (stages 3-6) -> h1B ----
  short8v h1B[8];
  #define T1S(t, S) { \
    f32x4 a[4] = {}; \
    PIPE(S, 4); \
    _Pragma("unroll") \
    for (int f = 0; f < 16; ++f) \
      a[f >> 2] = MM16(FRAG(S, f), xf[f & 3], a[f >> 2]); \
    cvt16(a[0], a[1], bLds + 256 + (t) * 64,      hi, h1B[2 * (t)]); \
    cvt16(a[2], a[3], bLds + 256 + (t) * 64 + 32, hi, h1B[2 * (t) + 1]); \
  }
  T1S(0, 3) T1S(1, 4) T1S(2, 5) T1S(3, 6)

  short8v h2B[4];
  #define T2S(s, S, BOFF) { \
    f32x4 u[2] = {}; \
    PIPE(S, 4); \
    _Pragma("unroll") \
    for (int f = 0; f < 16; ++f) \
      u[f >> 3] = MM16(FRAG(S, f), h1B[f & 7], u[f >> 3]); \
    cvt16(u[0], u[1], bLds + 512 + (BOFF) + 32 * (s), hi, h2B[s]); \
  }

  f32x4 wacc[8] = {};
  #define T3S(s, S, NW) { \
    PIPE(S, NW); \
    _Pragma("unroll") \
    for (int f = 0; f < 16; ++f) \
      wacc[f >> 1] = MM16(FRAG(S, f), h2B[2 * (s) + (f & 1)], wacc[f >> 1]); \
  }

  // T2a (7-10) -> T3a (11-12) -> T2b (13-16) -> T3b (17-18)
  T2S(0, 7, 0) T2S(1, 8, 0) T2S(2, 9, 0) T2S(3, 10, 0)
  T3S(0, 11, 4) T3S(1, 12, 4)
  T2S(0, 13, 128) T2S(1, 14, 128) T2S(2, 15, 128) T2S(3, 16, 128)
  T3S(0, 17, 4) T3S(1, 18, 0)

  // ---- epilogue: score + trajectory ----
  if (hi == 0 && valid) {
    float v = gw * (p0 + sb3[e]);
    if (OUTMODE == 0) scoreP[slotbase + row] = v; else atomicAdd(&score_out[tok], v);
  }
  if (valid) {
    if (OUTMODE == 0) {
      unsigned short* dst = trajP + (size_t)(slotbase + row) * 120;
      #pragma unroll
      for (int t = 0; t < 8; ++t)
        #pragma unroll
        for (int r = 0; r < 4; r += 2) {
          int unit = t * 16 + 4 * hi + r;
          if (unit + 1 < 120) {
            float a0 = gw * (wacc[t][r] + bLds[768 + unit]);
            float a1 = gw * (wacc[t][r + 1] + bLds[768 + unit + 1]);
            *(unsigned int*)(dst + unit) = (unsigned)f2bf(a0) | ((unsigned)f2bf(a1) << 16);
          }
        }
    } else {
      float* dst = traj_out + (size_t)tok * 120;
      #pragma unroll
      for (int t = 0; t < 8; ++t)
        #pragma unroll
        for (int r = 0; r < 4; ++r) {
          int unit = t * 16 + 4 * hi + r;
          if (unit < 120) atomicAdd(&dst[unit], gw * (wacc[t][r] + bLds[768 + unit]));
        }
    }
  }
}

// ---------------- combine: sum each token's 2 pair partials ----------------
__global__ __launch_bounds__(256) void combine_kernel(
    const int* __restrict__ pairIdx, const int* __restrict__ csum,
    const unsigned short* __restrict__ trajP, const float* __restrict__ scoreP,
    float* __restrict__ traj_out, float* __restrict__ score_out)
{
  int t = blockIdx.x * 256 + threadIdx.x;
  if (t >= N_TOK) return;
  int p0 = pairIdx[2 * t], p1 = pairIdx[2 * t + 1];
  int e0 = p0 / N_TOK, e1 = p1 / N_TOK;
  size_t s0 = (size_t)csum[e0] + (p0 - e0 * N_TOK);
  size_t s1 = (size_t)csum[e1] + (p1 - e1 * N_TOK);
  const unsigned short* r0 = trajP + s0 * 120;
  const unsigned short* r1 = trajP + s1 * 120;
  float* o = traj_out + (size_t)t * 120;
  #pragma unroll 6
  for (int i = 0; i < 30; ++i) {
    u16x4 a = *(const u16x4*)(r0 + i * 4);
    u16x4 b = *(const u16x4*)(r1 + i * 4);
    f32x4 v;
    #pragma unroll
    for (int jj = 0; jj < 4; ++jj) v[jj] = bf2f(a[jj]) + bf2f(b[jj]);
    *(f32x4*)(o + i * 4) = v;
  }
  score_out[t] = scoreP[s0] + scoreP[s1];
}

extern "C" void kernel_launch(void* const* d_in, const int* in_sizes, int n_in,
                              void* d_out, int out_size, void* d_ws, size_t ws_size,
                              hipStream_t stream) {
  (void)in_sizes; (void)n_in; (void)out_size;
  const float* x   = (const float*)d_in[0];
  const float* rW1 = (const float*)d_in[1];
  const float* rb1 = (const float*)d_in[2];
  const float* rW2 = (const float*)d_in[3];
  const float* rb2 = (const float*)d_in[4];
  const float* rW3 = (const float*)d_in[5];
  const float* rb3 = (const float*)d_in[6];
  const float* tW1 = (const float*)d_in[7];
  const float* tb1 = (const float*)d_in[8];
  const float* tW2 = (const float*)d_in[9];
  const float* tb2 = (const float*)d_in[10];
  const float* tW3 = (const float*)d_in[11];
  const float* tb3 = (const float*)d_in[12];
  const float* sW1 = (const float*)d_in[13];
  const float* sb1 = (const float*)d_in[14];
  const float* sW2 = (const float*)d_in[15];
  const float* sb2 = (const float*)d_in[16];
  const float* sW3 = (const float*)d_in[17];
  const float* sb3 = (const float*)d_in[18];
  float* out = (float*)d_out;

  // workspace carve (bytes)
  char* wsb = (char*)d_ws;
  int*   cnt     = (int*)(wsb + 0);
  float* probsum = (float*)(wsb + 32);
  int*   csum    = (int*)(wsb + 64);
  int*   pairTok = (int*)(wsb + 96);
  float* pairW   = (float*)(wsb + 96 + (size_t)6 * N_TOK * 4);
  int*   pairIdx = (int*)(wsb + 96 + (size_t)12 * N_TOK * 4);
  float* scoreP  = (float*)(wsb + 96 + (size_t)14 * N_TOK * 4);
  unsigned short* blob = (unsigned short*)(wsb + 96 + (size_t)16 * N_TOK * 4);
  unsigned short* trajP = (unsigned short*)(wsb + 96 + (size_t)16 * N_TOK * 4 + (size_t)6 * PER_E * 2);
  size_t need = 96 + (size_t)16 * N_TOK * 4 + (size_t)6 * PER_E * 2 + (size_t)2 * N_TOK * 120 * 2;
  bool scratch = ws_size >= need;

  hipMemsetAsync(wsb, 0, 96, stream);
  if (!scratch) hipMemsetAsync(d_out, 0, (size_t)(N_TOK * 121) * 4, stream);

  prep_weights<<<(6 * PER_E) / 256, 256, 0, stream>>>(tW1, tW2, tW3, sW1, sW2, blob);
  router_kernel<<<N_TOK / 32, 256, 0, stream>>>(x, rW1, rb1, rW2, rb2, rW3, rb3,
                                                out + PROB_OFF, pairTok, pairW, pairIdx, cnt, probsum);
  aux_kernel<<<1, 64, 0, stream>>>(probsum, cnt, csum, out + AUX_OFF);
  if (scratch) {
    expert_kernel<0><<<dim3(N_TOK / 64, 6), 256, 0, stream>>>(
        x, blob, tb1, tb2, tb3, sb1, sb2, sW3, sb3, pairTok, pairW, cnt, csum,
        out + TRAJ_OFF, out + SCORE_OFF, trajP, scoreP);
    combine_kernel<<<N_TOK / 256, 256, 0, stream>>>(pairIdx, csum, trajP, scoreP,
                                                    out + TRAJ_OFF, out + SCORE_OFF);
  } else {
    expert_kernel<1><<<dim3(N_TOK / 64, 6), 256, 0, stream>>>(
        x, blob, tb1, tb2, tb3, sb1, sb2, sW3, sb3, pairTok, pairW, cnt, csum,
        out + TRAJ_OFF, out + SCORE_OFF, trajP, scoreP);
  }
}

// Round 9
// 246.808 us; speedup vs baseline: 2.7336x; 1.5661x over previous
//
#include <hip/hip_runtime.h>

#define N_TOK 49152
#define PER_E 155648      // 19 stages * 8192 bf16 elems per expert
#define NSTAGE 19

// d_out float offsets
#define TRAJ_OFF 0
#define SCORE_OFF 5898240
#define AUX_OFF  5947392
#define PROB_OFF 5947393

typedef __attribute__((ext_vector_type(8))) short short8v;
typedef __attribute__((ext_vector_type(4))) float f32x4;
typedef __attribute__((ext_vector_type(4))) unsigned short u16x4;

typedef __attribute__((address_space(3))) unsigned char lds_byte;
typedef __attribute__((address_space(1))) const unsigned char gl_byte;

__device__ __forceinline__ unsigned short f2bf(float f) {
  unsigned int u = __float_as_uint(f);
  u = (u + 0x7FFFu + ((u >> 16) & 1u)) >> 16;
  return (unsigned short)u;
}
__device__ __forceinline__ float bf2f(unsigned short h) {
  return __uint_as_float(((unsigned int)h) << 16);
}
// branch-free erf (A&S 7.1.26, abs err <1.5e-7) -> exact-gelu replacement
__device__ __forceinline__ float geluf(float v) {
  float x = v * 0.70710678118654752f;
  float ax = fabsf(x);
  float t = __builtin_amdgcn_rcpf(fmaf(0.3275911f, ax, 1.0f));
  float p = t * fmaf(t, fmaf(t, fmaf(t, fmaf(t, 1.061405429f, -1.453152027f),
                                     1.421413741f), -0.284496736f), 0.254829592f);
  float er = 1.0f - p * __expf(-ax * ax);
  er = copysignf(er, x);
  return 0.5f * v * (1.0f + er);
}

// ---------------- weight prep: fp32 -> bf16, A-fragment stages for 16x16x32 ----------------
// (verified R7/R8: absmax 9.8e-4)
__global__ __launch_bounds__(256) void prep_weights(
    const float* __restrict__ tW1, const float* __restrict__ tW2, const float* __restrict__ tW3,
    const float* __restrict__ sW1, const float* __restrict__ sW2,
    unsigned short* __restrict__ blob)
{
  int id = blockIdx.x * 256 + threadIdx.x;
  if (id >= 6 * PER_E) return;
  int e = id / PER_E;
  int r = id - e * PER_E;
  int p = r >> 13;
  int q = r & 8191;
  int f = q >> 9;
  int l = (q >> 3) & 63;
  int j = q & 7;
  int hi = l >> 4, rl = l & 15;
  const float* src; int N, tile, ks; bool perm;
  if (p < 2)       { src = sW1 + e * 16384; N = 128; tile = 4 * p + (f >> 2);        ks = f & 3; perm = false; }
  else if (p == 2) { src = sW2 + e * 8192;  N = 64;  tile = f >> 2;                  ks = f & 3; perm = true;  }
  else if (p < 7)  { src = tW1 + e * 32768; N = 256; tile = 4 * (p - 3) + (f >> 2);  ks = f & 3; perm = false; }
  else if (p < 11) { src = tW2 + e * 65536; N = 256; tile = 2 * (p - 7) + (f >> 3);  ks = f & 7; perm = true;  }
  else if (p < 13) { src = tW3 + e * 30720; N = 120; tile = f >> 1;  ks = 2 * (p - 11) + (f & 1); perm = true; }
  else if (p < 17) { src = tW2 + e * 65536; N = 256; tile = 8 + 2 * (p - 13) + (f >> 3); ks = f & 7; perm = true; }
  else             { src = tW3 + e * 30720; N = 120; tile = f >> 1;  ks = 4 + 2 * (p - 17) + (f & 1); perm = true; }
  int k = ks * 32 + (perm ? (16 * (j >> 2) + 4 * hi + (j & 3)) : (8 * hi + j));
  int unit = tile * 16 + rl;
  blob[id] = f2bf(unit < N ? src[k * N + unit] : 0.0f);
}

// ---------------- fused fp32 router ----------------
__global__ __launch_bounds__(256) void router_kernel(
    const float* __restrict__ x,
    const float* __restrict__ rW1, const float* __restrict__ rb1,
    const float* __restrict__ rW2, const float* __restrict__ rb2,
    const float* __restrict__ rW3, const float* __restrict__ rb3,
    float* __restrict__ probs_out,
    int* __restrict__ pairTok, float* __restrict__ pairW, int* __restrict__ pairIdx,
    int* __restrict__ cnt, float* __restrict__ probsum)
{
  __shared__ float xs[32][128];
  __shared__ float h1[32][256];
  __shared__ float h2[32][132];
  __shared__ float lg[32][8];
  __shared__ float psum[8];
  __shared__ int lcnt[8], gbase[8];

  int tid = threadIdx.x;
  int tok0 = blockIdx.x * 32;

  for (int i = tid; i < 32 * 32; i += 256) {
    int row = i >> 5, c4 = i & 31;
    *(f32x4*)&xs[row][c4 * 4] = *(const f32x4*)(x + (size_t)(tok0 + row) * 128 + c4 * 4);
  }
  if (tid < 8) { psum[tid] = 0.f; lcnt[tid] = 0; }
  __syncthreads();

  {
    int u0 = (tid & 63) * 4;
    int t0 = (tid >> 6) * 8;
    float a[8][4];
    #pragma unroll
    for (int t = 0; t < 8; ++t)
      #pragma unroll
      for (int u = 0; u < 4; ++u) a[t][u] = 0.f;
    for (int db = 0; db < 32; ++db) {
      int d = db * 4;
      f32x4 wv[4];
      #pragma unroll
      for (int dd = 0; dd < 4; ++dd) wv[dd] = *(const f32x4*)(rW1 + (size_t)(d + dd) * 256 + u0);
      #pragma unroll
      for (int tt = 0; tt < 8; ++tt) {
        f32x4 xv = *(const f32x4*)&xs[t0 + tt][d];
        #pragma unroll
        for (int dd = 0; dd < 4; ++dd)
          #pragma unroll
          for (int uu = 0; uu < 4; ++uu) a[tt][uu] += xv[dd] * wv[dd][uu];
      }
    }
    f32x4 bv = *(const f32x4*)(rb1 + u0);
    #pragma unroll
    for (int tt = 0; tt < 8; ++tt) {
      f32x4 o;
      #pragma unroll
      for (int uu = 0; uu < 4; ++uu) o[uu] = geluf(a[tt][uu] + bv[uu]);
      *(f32x4*)&h1[t0 + tt][u0] = o;
    }
  }
  __syncthreads();

  {
    int u0 = (tid & 31) * 4;
    int t0 = (tid >> 5) * 4;
    float a[4][4];
    #pragma unroll
    for (int t = 0; t < 4; ++t)
      #pragma unroll
      for (int u = 0; u < 4; ++u) a[t][u] = 0.f;
    for (int db = 0; db < 64; ++db) {
      int d = db * 4;
      f32x4 wv[4];
      #pragma unroll
      for (int dd = 0; dd < 4; ++dd) wv[dd] = *(const f32x4*)(rW2 + (size_t)(d + dd) * 128 + u0);
      #pragma unroll
      for (int tt = 0; tt < 4; ++tt) {
        f32x4 xv = *(const f32x4*)&h1[t0 + tt][d];
        #pragma unroll
        for (int dd = 0; dd < 4; ++dd)
          #pragma unroll
          for (int uu = 0; uu < 4; ++uu) a[tt][uu] += xv[dd] * wv[dd][uu];
      }
    }
    f32x4 bv = *(const f32x4*)(rb2 + u0);
    #pragma unroll
    for (int tt = 0; tt < 4; ++tt) {
      f32x4 o;
      #pragma unroll
      for (int uu = 0; uu < 4; ++uu) o[uu] = geluf(a[tt][uu] + bv[uu]);
      *(f32x4*)&h2[t0 + tt][u0] = o;
    }
  }
  __syncthreads();

  if (tid < 192) {
    int t = tid / 6, e = tid - t * 6;
    float s = rb3[e];
    for (int d = 0; d < 128; ++d) s += h2[t][d] * rW3[d * 6 + e];
    lg[t][e] = s;
  }
  __syncthreads();

  int i1 = 0, i2 = 0, lp1 = 0, lp2 = 0;
  float w1 = 0.f, w2 = 0.f;
  int myTok = tok0 + tid;
  if (tid < 32) {
    float l0[6];
    #pragma unroll
    for (int e = 0; e < 6; ++e) l0[e] = lg[tid][e];
    float m = l0[0];
    #pragma unroll
    for (int e = 1; e < 6; ++e) m = fmaxf(m, l0[e]);
    float pe[6]; float ssum = 0.f;
    #pragma unroll
    for (int e = 0; e < 6; ++e) { pe[e] = expf(l0[e] - m); ssum += pe[e]; }
    float inv = 1.f / ssum;
    #pragma unroll
    for (int e = 0; e < 6; ++e) {
      float pr = pe[e] * inv;
      probs_out[(size_t)myTok * 6 + e] = pr;
      atomicAdd(&psum[e], pr);
    }
    float v1 = l0[0]; i1 = 0; float v2 = -1e30f; i2 = -1;
    #pragma unroll
    for (int e = 1; e < 6; ++e) {
      float v = l0[e];
      if (v > v1) { v2 = v1; i2 = i1; v1 = v; i1 = e; }
      else if (v > v2) { v2 = v; i2 = e; }
    }
    float e2 = expf(v2 - v1);
    float denom = 1.f / (1.f + e2);
    w1 = denom; w2 = e2 * denom;
    lp1 = atomicAdd(&lcnt[i1], 1);
    lp2 = atomicAdd(&lcnt[i2], 1);
  }
  __syncthreads();
  if (tid < 6) gbase[tid] = atomicAdd(&cnt[tid], lcnt[tid]);
  __syncthreads();
  if (tid < 32) {
    int g1 = gbase[i1] + lp1, g2 = gbase[i2] + lp2;
    pairTok[i1 * N_TOK + g1] = myTok; pairW[i1 * N_TOK + g1] = w1;
    pairTok[i2 * N_TOK + g2] = myTok; pairW[i2 * N_TOK + g2] = w2;
    pairIdx[2 * myTok]     = i1 * N_TOK + g1;
    pairIdx[2 * myTok + 1] = i2 * N_TOK + g2;
  }
  if (tid < 6) atomicAdd(&probsum[tid], psum[tid]);
}

// ---------------- aux loss + csum ----------------
__global__ void aux_kernel(const float* __restrict__ probsum, const int* __restrict__ cnt,
                           int* __restrict__ csum, float* __restrict__ auxout)
{
  if (threadIdx.x == 0 && blockIdx.x == 0) {
    int s = 0;
    for (int e = 0; e < 6; ++e) { csum[e] = s; s += cnt[e]; }
    float ent = 0.f, l2 = 0.f;
    for (int e = 0; e < 6; ++e) {
      float avg = probsum[e] / (float)N_TOK;
      ent -= avg * logf(avg + 1e-8f);
      float d = avg - (1.0f / 6.0f);
      l2 += d * d;
    }
    l2 *= (1.0f / 6.0f);
    auxout[0] = -ent * 0.01f + 0.01f * l2;
  }
}

// ---------------- expert kernel ----------------
__device__ __forceinline__ f32x4 MM16(short8v a, short8v b, f32x4 c) {
  return __builtin_amdgcn_mfma_f32_16x16x32_bf16(a, b, c, 0, 0, 0);
}

__device__ __forceinline__ void cvt16(f32x4 aE, f32x4 aO, const float* bp, int hi, short8v& fr) {
  #pragma unroll
  for (int j = 0; j < 8; ++j) {
    float v = (j < 4) ? aE[j & 3] : aO[j & 3];
    int unit = 16 * (j >> 2) + 4 * hi + (j & 3);
    fr[j] = (short)f2bf(geluf(v + bp[unit]));
  }
}

// 8 waves: each stages 2KB (2 x 1KB DMA) of the 16KB stage
#define STAGE(s) do { \
    const unsigned short* gsrc_ = eblob + (s) * 8192 + w * 1024 + lane * 8; \
    unsigned short* ldst_ = &wlds[((s) % 3) * 8192 + w * 1024]; \
    _Pragma("unroll") \
    for (int i_ = 0; i_ < 2; ++i_) \
      __builtin_amdgcn_global_load_lds((gl_byte*)(gsrc_ + i_ * 512), (lds_byte*)(ldst_ + i_ * 512), 16, 0, 0); \
  } while (0)

// wait stage-s loads (2 of s+1 in flight), barrier, THEN issue stage s+2
#define PIPE(s, nw) do { \
    asm volatile("s_waitcnt vmcnt(" #nw ")" ::: "memory"); \
    __builtin_amdgcn_sched_barrier(0); \
    __builtin_amdgcn_s_barrier(); \
    __builtin_amdgcn_sched_barrier(0); \
    if ((s) + 2 < NSTAGE) STAGE((s) + 2); \
  } while (0)

#define FRAG(s, f) (*(const short8v*)(&wlds[((s) % 3) * 8192 + (f) * 512 + lane * 8]))

template<int OUTMODE>   // 0 = scratch pair partials, 1 = atomicAdd into d_out
__global__ __launch_bounds__(512) void expert_kernel(
    const float* __restrict__ x,
    const unsigned short* __restrict__ blob,
    const float* __restrict__ tb1, const float* __restrict__ tb2, const float* __restrict__ tb3,
    const float* __restrict__ sb1, const float* __restrict__ sb2,
    const float* __restrict__ sW3, const float* __restrict__ sb3,
    const int* __restrict__ pairTok, const float* __restrict__ pairW,
    const int* __restrict__ cnt, const int* __restrict__ csum,
    float* __restrict__ traj_out, float* __restrict__ score_out,
    unsigned short* __restrict__ trajP, float* __restrict__ scoreP)
{
  int e = blockIdx.y;
  int base = blockIdx.x * 128;
  int count = cnt[e];
  if (base >= count) return;

  __shared__ __align__(16) unsigned short wlds[3 * 8192];   // 48KB ring
  __shared__ float bLds[896];
  __shared__ int   toksLds[128];
  __shared__ float gwsLds[128];

  int tid = threadIdx.x;
  int lane = tid & 63;
  int w = tid >> 6;            // 8 waves
  int col = lane & 15;
  int hi = lane >> 4;
  const unsigned short* eblob = blob + (size_t)e * PER_E;
  int slotbase = csum[e] + base;

  if (tid < 128) {
    int idx = e * N_TOK + base + ((base + tid < count) ? tid : 0);
    toksLds[tid] = pairTok[idx];
    gwsLds[tid] = (base + tid < count) ? pairW[idx] : 0.f;
  }
  // biases -> LDS: [0,128) sb1 | [128,192) sb2 | [192,256) sW3 | [256,512) tb1 | [512,768) tb2 | [768,888) tb3
  if (tid < 128) bLds[tid] = sb1[e * 128 + tid];
  if (tid < 64)  bLds[128 + tid] = sb2[e * 64 + tid];
  if (tid < 64)  bLds[192 + tid] = sW3[e * 64 + tid];
  if (tid < 256) { bLds[256 + tid] = tb1[e * 256 + tid]; bLds[512 + tid] = tb2[e * 256 + tid]; }
  if (tid < 120) bLds[768 + tid] = tb3[e * 120 + tid];
  __syncthreads();

  int row = w * 16 + col;
  int tok = toksLds[row];
  bool valid = (base + row < count);
  float gw = gwsLds[row];

  // gather X -> B-frags (token col = lane&15, k = ks*32 + hi*8 + j); retired before pipeline
  short8v xf[4];
  {
    const float* px = x + (size_t)tok * 128 + hi * 8;
    #pragma unroll
    for (int ks = 0; ks < 4; ++ks) {
      f32x4 lo = *(const f32x4*)(px + ks * 32);
      f32x4 hv = *(const f32x4*)(px + ks * 32 + 4);
      short8v t;
      #pragma unroll
      for (int j = 0; j < 4; ++j) { t[j] = (short)f2bf(lo[j]); t[4 + j] = (short)f2bf(hv[j]); }
      xf[ks] = t;
    }
  }

  STAGE(0);
  STAGE(1);

  short8v sB[4];
  // ---- S1: sW1 @ X (stages 0-1) ----
  {
    f32x4 a[4] = {};
    PIPE(0, 2);
    #pragma unroll
    for (int f = 0; f < 16; ++f)
      a[f >> 2] = MM16(FRAG(0, f), xf[f & 3], a[f >> 2]);
    cvt16(a[0], a[1], bLds + 0,  hi, sB[0]);  cvt16(a[2], a[3], bLds + 32, hi, sB[1]);
    f32x4 b[4] = {};
    PIPE(1, 2);
    #pragma unroll
    for (int f = 0; f < 16; ++f)
      b[f >> 2] = MM16(FRAG(1, f), xf[f & 3], b[f >> 2]);
    cvt16(b[0], b[1], bLds + 64, hi, sB[2]);  cvt16(b[2], b[3], bLds + 96, hi, sB[3]);
  }

  // ---- S2: sW2 @ SH1 (stage 2) -> score (held in regs) ----
  float p0 = 0.f;
  {
    f32x4 q[4] = {};
    PIPE(2, 2);
    #pragma unroll
    for (int f = 0; f < 16; ++f)
      q[f >> 2] = MM16(FRAG(2, f), sB[f & 3], q[f >> 2]);
    #pragma unroll
    for (int t = 0; t < 4; ++t)
      #pragma unroll
      for (int r = 0; r < 4; ++r) {
        int unit = t * 16 + 4 * hi + r;
        p0 += geluf(q[t][r] + bLds[128 + unit]) * bLds[192 + unit];
      }
    p0 += __shfl_xor(p0, 16); p0 += __shfl_xor(p0, 32);
  }

  // ---- T1: tW1 @ X (stages 3-6) -> h1B ----
  short8v h1B[8];
  #define T1S(t, S) { \
    f32x4 a[4] = {}; \
    PIPE(S, 2); \
    _Pragma("unroll") \
    for (int f = 0; f < 16; ++f) \
      a[f >> 2] = MM16(FRAG(S, f), xf[f & 3], a[f >> 2]); \
    cvt16(a[0], a[1], bLds + 256 + (t) * 64,      hi, h1B[2 * (t)]); \
    cvt16(a[2], a[3], bLds + 256 + (t) * 64 + 32, hi, h1B[2 * (t) + 1]); \
  }
  T1S(0, 3) T1S(1, 4) T1S(2, 5) T1S(3, 6)

  short8v h2B[4];
  #define T2S(s, S, BOFF) { \
    f32x4 u[2] = {}; \
    PIPE(S, 2); \
    _Pragma("unroll") \
    for (int f = 0; f < 16; ++f) \
      u[f >> 3] = MM16(FRAG(S, f), h1B[f & 7], u[f >> 3]); \
    cvt16(u[0], u[1], bLds + 512 + (BOFF) + 32 * (s), hi, h2B[s]); \
  }

  f32x4 wacc[8] = {};
  #define T3S(s, S, NW) { \
    PIPE(S, NW); \
    _Pragma("unroll") \
    for (int f = 0; f < 16; ++f) \
      wacc[f >> 1] = MM16(FRAG(S, f), h2B[2 * (s) + (f & 1)], wacc[f >> 1]); \
  }

  // T2a (7-10) -> T3a (11-12) -> T2b (13-16) -> T3b (17-18)
  T2S(0, 7, 0) T2S(1, 8, 0) T2S(2, 9, 0) T2S(3, 10, 0)
  T3S(0, 11, 2) T3S(1, 12, 2)
  T2S(0, 13, 128) T2S(1, 14, 128) T2S(2, 15, 128) T2S(3, 16, 128)
  T3S(0, 17, 2) T3S(1, 18, 0)

  // ---- epilogue: score + trajectory ----
  if (hi == 0 && valid) {
    float v = gw * (p0 + sb3[e]);
    if (OUTMODE == 0) scoreP[slotbase + row] = v; else atomicAdd(&score_out[tok], v);
  }
  if (valid) {
    if (OUTMODE == 0) {
      unsigned short* dst = trajP + (size_t)(slotbase + row) * 120;
      #pragma unroll
      for (int t = 0; t < 8; ++t)
        #pragma unroll
        for (int r = 0; r < 4; r += 2) {
          int unit = t * 16 + 4 * hi + r;
          if (unit + 1 < 120) {
            float a0 = gw * (wacc[t][r] + bLds[768 + unit]);
            float a1 = gw * (wacc[t][r + 1] + bLds[768 + unit + 1]);
            *(unsigned int*)(dst + unit) = (unsigned)f2bf(a0) | ((unsigned)f2bf(a1) << 16);
          }
        }
    } else {
      float* dst = traj_out + (size_t)tok * 120;
      #pragma unroll
      for (int t = 0; t < 8; ++t)
        #pragma unroll
        for (int r = 0; r < 4; ++r) {
          int unit = t * 16 + 4 * hi + r;
          if (unit < 120) atomicAdd(&dst[unit], gw * (wacc[t][r] + bLds[768 + unit]));
        }
    }
  }
}

// ---------------- combine: sum each token's 2 pair partials ----------------
__global__ __launch_bounds__(256) void combine_kernel(
    const int* __restrict__ pairIdx, const int* __restrict__ csum,
    const unsigned short* __restrict__ trajP, const float* __restrict__ scoreP,
    float* __restrict__ traj_out, float* __restrict__ score_out)
{
  int t = blockIdx.x * 256 + threadIdx.x;
  if (t >= N_TOK) return;
  int p0 = pairIdx[2 * t], p1 = pairIdx[2 * t + 1];
  int e0 = p0 / N_TOK, e1 = p1 / N_TOK;
  size_t s0 = (size_t)csum[e0] + (p0 - e0 * N_TOK);
  size_t s1 = (size_t)csum[e1] + (p1 - e1 * N_TOK);
  const unsigned short* r0 = trajP + s0 * 120;
  const unsigned short* r1 = trajP + s1 * 120;
  float* o = traj_out + (size_t)t * 120;
  #pragma unroll 6
  for (int i = 0; i < 30; ++i) {
    u16x4 a = *(const u16x4*)(r0 + i * 4);
    u16x4 b = *(const u16x4*)(r1 + i * 4);
    f32x4 v;
    #pragma unroll
    for (int jj = 0; jj < 4; ++jj) v[jj] = bf2f(a[jj]) + bf2f(b[jj]);
    *(f32x4*)(o + i * 4) = v;
  }
  score_out[t] = scoreP[s0] + scoreP[s1];
}

extern "C" void kernel_launch(void* const* d_in, const int* in_sizes, int n_in,
                              void* d_out, int out_size, void* d_ws, size_t ws_size,
                              hipStream_t stream) {
  (void)in_sizes; (void)n_in; (void)out_size;
  const float* x   = (const float*)d_in[0];
  const float* rW1 = (const float*)d_in[1];
  const float* rb1 = (const float*)d_in[2];
  const float* rW2 = (const float*)d_in[3];
  const float* rb2 = (const float*)d_in[4];
  const float* rW3 = (const float*)d_in[5];
  const float* rb3 = (const float*)d_in[6];
  const float* tW1 = (const float*)d_in[7];
  const float* tb1 = (const float*)d_in[8];
  const float* tW2 = (const float*)d_in[9];
  const float* tb2 = (const float*)d_in[10];
  const float* tW3 = (const float*)d_in[11];
  const float* tb3 = (const float*)d_in[12];
  const float* sW1 = (const float*)d_in[13];
  const float* sb1 = (const float*)d_in[14];
  const float* sW2 = (const float*)d_in[15];
  const float* sb2 = (const float*)d_in[16];
  const float* sW3 = (const float*)d_in[17];
  const float* sb3 = (const float*)d_in[18];
  float* out = (float*)d_out;

  // workspace carve (bytes)
  char* wsb = (char*)d_ws;
  int*   cnt     = (int*)(wsb + 0);
  float* probsum = (float*)(wsb + 32);
  int*   csum    = (int*)(wsb + 64);
  int*   pairTok = (int*)(wsb + 96);
  float* pairW   = (float*)(wsb + 96 + (size_t)6 * N_TOK * 4);
  int*   pairIdx = (int*)(wsb + 96 + (size_t)12 * N_TOK * 4);
  float* scoreP  = (float*)(wsb + 96 + (size_t)14 * N_TOK * 4);
  unsigned short* blob = (unsigned short*)(wsb + 96 + (size_t)16 * N_TOK * 4);
  unsigned short* trajP = (unsigned short*)(wsb + 96 + (size_t)16 * N_TOK * 4 + (size_t)6 * PER_E * 2);
  size_t need = 96 + (size_t)16 * N_TOK * 4 + (size_t)6 * PER_E * 2 + (size_t)2 * N_TOK * 120 * 2;
  bool scratch = ws_size >= need;

  hipMemsetAsync(wsb, 0, 96, stream);
  if (!scratch) hipMemsetAsync(d_out, 0, (size_t)(N_TOK * 121) * 4, stream);

  prep_weights<<<(6 * PER_E) / 256, 256, 0, stream>>>(tW1, tW2, tW3, sW1, sW2, blob);
  router_kernel<<<N_TOK / 32, 256, 0, stream>>>(x, rW1, rb1, rW2, rb2, rW3, rb3,
                                                out + PROB_OFF, pairTok, pairW, pairIdx, cnt, probsum);
  aux_kernel<<<1, 64, 0, stream>>>(probsum, cnt, csum, out + AUX_OFF);
  if (scratch) {
    expert_kernel<0><<<dim3(N_TOK / 128, 6), 512, 0, stream>>>(
        x, blob, tb1, tb2, tb3, sb1, sb2, sW3, sb3, pairTok, pairW, cnt, csum,
        out + TRAJ_OFF, out + SCORE_OFF, trajP, scoreP);
    combine_kernel<<<N_TOK / 256, 256, 0, stream>>>(pairIdx, csum, trajP, scoreP,
                                                    out + TRAJ_OFF, out + SCORE_OFF);
  } else {
    expert_kernel<1><<<dim3(N_TOK / 128, 6), 512, 0, stream>>>(
        x, blob, tb1, tb2, tb3, sb1, sb2, sW3, sb3, pairTok, pairW, cnt, csum,
        out + TRAJ_OFF, out + SCORE_OFF, trajP, scoreP);
  }
}

// Round 10
// 186.085 us; speedup vs baseline: 3.6256x; 1.3263x over previous
//
#include <hip/hip_runtime.h>

#define N_TOK 49152
#define PER_E 155648      // expert blob: 19 stages * 8192 bf16 elems per expert
#define NSTAGE 19
#define RSTAGES 24        // router blob: 24 stages * 8192 bf16 elems

// d_out float offsets
#define TRAJ_OFF 0
#define SCORE_OFF 5898240
#define AUX_OFF  5947392
#define PROB_OFF 5947393

typedef __attribute__((ext_vector_type(8))) short short8v;
typedef __attribute__((ext_vector_type(4))) float f32x4;
typedef __attribute__((ext_vector_type(4))) unsigned short u16x4;

typedef __attribute__((address_space(3))) unsigned char lds_byte;
typedef __attribute__((address_space(1))) const unsigned char gl_byte;

__device__ __forceinline__ unsigned short f2bf(float f) {
  unsigned int u = __float_as_uint(f);
  u = (u + 0x7FFFu + ((u >> 16) & 1u)) >> 16;
  return (unsigned short)u;
}
__device__ __forceinline__ float bf2f(unsigned short h) {
  return __uint_as_float(((unsigned int)h) << 16);
}
// branch-free erf (A&S 7.1.26, abs err <1.5e-7) -> exact-gelu replacement
__device__ __forceinline__ float geluf(float v) {
  float x = v * 0.70710678118654752f;
  float ax = fabsf(x);
  float t = __builtin_amdgcn_rcpf(fmaf(0.3275911f, ax, 1.0f));
  float p = t * fmaf(t, fmaf(t, fmaf(t, fmaf(t, 1.061405429f, -1.453152027f),
                                     1.421413741f), -0.284496736f), 0.254829592f);
  float er = 1.0f - p * __expf(-ax * ax);
  er = copysignf(er, x);
  return 0.5f * v * (1.0f + er);
}

// ---------------- expert weight prep (verified R7-R9) ----------------
__global__ __launch_bounds__(256) void prep_weights(
    const float* __restrict__ tW1, const float* __restrict__ tW2, const float* __restrict__ tW3,
    const float* __restrict__ sW1, const float* __restrict__ sW2,
    unsigned short* __restrict__ blob)
{
  int id = blockIdx.x * 256 + threadIdx.x;
  if (id >= 6 * PER_E) return;
  int e = id / PER_E;
  int r = id - e * PER_E;
  int p = r >> 13;
  int q = r & 8191;
  int f = q >> 9;
  int l = (q >> 3) & 63;
  int j = q & 7;
  int hi = l >> 4, rl = l & 15;
  const float* src; int N, tile, ks; bool perm;
  if (p < 2)       { src = sW1 + e * 16384; N = 128; tile = 4 * p + (f >> 2);        ks = f & 3; perm = false; }
  else if (p == 2) { src = sW2 + e * 8192;  N = 64;  tile = f >> 2;                  ks = f & 3; perm = true;  }
  else if (p < 7)  { src = tW1 + e * 32768; N = 256; tile = 4 * (p - 3) + (f >> 2);  ks = f & 3; perm = false; }
  else if (p < 11) { src = tW2 + e * 65536; N = 256; tile = 2 * (p - 7) + (f >> 3);  ks = f & 7; perm = true;  }
  else if (p < 13) { src = tW3 + e * 30720; N = 120; tile = f >> 1;  ks = 2 * (p - 11) + (f & 1); perm = true; }
  else if (p < 17) { src = tW2 + e * 65536; N = 256; tile = 8 + 2 * (p - 13) + (f >> 3); ks = f & 7; perm = true; }
  else             { src = tW3 + e * 30720; N = 120; tile = f >> 1;  ks = 4 + 2 * (p - 17) + (f & 1); perm = true; }
  int k = ks * 32 + (perm ? (16 * (j >> 2) + 4 * hi + (j & 3)) : (8 * hi + j));
  int unit = tile * 16 + rl;
  blob[id] = f2bf(unit < N ? src[k * N + unit] : 0.0f);
}

// ---------------- router weight prep: 3-way bf16 split, A-frag stages ----------------
// stages 0-11: rW1 (chunk c=p/3: tiles 4c+(f>>2), ks=f&3, linear) part=p%3
// stages 12-23: rW2 (chunk c: tiles 2c+(f>>3), ks=f&7, perm) part=(p-12)%3
__global__ __launch_bounds__(256) void prep_router(
    const float* __restrict__ rW1, const float* __restrict__ rW2,
    unsigned short* __restrict__ rblob)
{
  int id = blockIdx.x * 256 + threadIdx.x;
  if (id >= RSTAGES * 8192) return;
  int p = id >> 13;
  int q = id & 8191;
  int f = q >> 9;
  int l = (q >> 3) & 63;
  int j = q & 7;
  int hi = l >> 4, rl = l & 15;
  const float* src; int N, tile, ks, part; bool perm;
  if (p < 12) { int c = p / 3; part = p % 3; src = rW1; N = 256; tile = 4 * c + (f >> 2); ks = f & 3; perm = false; }
  else        { int c = (p - 12) / 3; part = (p - 12) % 3; src = rW2; N = 128; tile = 2 * c + (f >> 3); ks = f & 7; perm = true; }
  int k = ks * 32 + (perm ? (16 * (j >> 2) + 4 * hi + (j & 3)) : (8 * hi + j));
  int unit = tile * 16 + rl;
  float v = (unit < N) ? src[k * N + unit] : 0.0f;
  unsigned short b0 = f2bf(v);
  float r1 = v - bf2f(b0);
  unsigned short b1 = f2bf(r1);
  float r2 = r1 - bf2f(b1);
  unsigned short b2 = f2bf(r2);
  rblob[id] = (part == 0) ? b0 : ((part == 1) ? b1 : b2);
}

// ---------------- shared MFMA helpers ----------------
__device__ __forceinline__ f32x4 MM16(short8v a, short8v b, f32x4 c) {
  return __builtin_amdgcn_mfma_f32_16x16x32_bf16(a, b, c, 0, 0, 0);
}
// two 16-unit acc tiles + bias -> gelu -> one next-layer B-frag (perm-absorbed)
__device__ __forceinline__ void cvt16(f32x4 aE, f32x4 aO, const float* bp, int hi, short8v& fr) {
  #pragma unroll
  for (int j = 0; j < 8; ++j) {
    float v = (j < 4) ? aE[j & 3] : aO[j & 3];
    int unit = 16 * (j >> 2) + 4 * hi + (j & 3);
    fr[j] = (short)f2bf(geluf(v + bp[unit]));
  }
}
// same, but 2-way-split output (hi + lo frags)
__device__ __forceinline__ void cvt16s(f32x4 aE, f32x4 aO, const float* bp, int hi,
                                       short8v& f0, short8v& f1) {
  #pragma unroll
  for (int j = 0; j < 8; ++j) {
    float v = (j < 4) ? aE[j & 3] : aO[j & 3];
    int unit = 16 * (j >> 2) + 4 * hi + (j & 3);
    float g = geluf(v + bp[unit]);
    unsigned short b0 = f2bf(g);
    f0[j] = (short)b0;
    f1[j] = (short)f2bf(g - bf2f(b0));
  }
}

#define FRAG(s, f) (*(const short8v*)(&wlds[((s) % 3) * 8192 + (f) * 512 + lane * 8]))

// ---------------- MFMA router: split-bf16 fp32-grade logits ----------------
#define RSTAGE(s) do { \
    const unsigned short* gsrc_ = rblob + (s) * 8192 + w * 1024 + lane * 8; \
    unsigned short* ldst_ = &wlds[((s) % 3) * 8192 + w * 1024]; \
    _Pragma("unroll") \
    for (int i_ = 0; i_ < 2; ++i_) \
      __builtin_amdgcn_global_load_lds((gl_byte*)(gsrc_ + i_ * 512), (lds_byte*)(ldst_ + i_ * 512), 16, 0, 0); \
  } while (0)

#define RPIPE(s, nw) do { \
    asm volatile("s_waitcnt vmcnt(" #nw ")" ::: "memory"); \
    __builtin_amdgcn_sched_barrier(0); \
    __builtin_amdgcn_s_barrier(); \
    __builtin_amdgcn_sched_barrier(0); \
    if ((s) + 2 < RSTAGES) RSTAGE((s) + 2); \
  } while (0)

__global__ __launch_bounds__(512) void router_mfma(
    const float* __restrict__ x, const unsigned short* __restrict__ rblob,
    const float* __restrict__ rb1, const float* __restrict__ rb2,
    const float* __restrict__ rW3, const float* __restrict__ rb3,
    float* __restrict__ probs_out,
    int* __restrict__ pairTok, float* __restrict__ pairW, int* __restrict__ pairIdx,
    int* __restrict__ cnt, float* __restrict__ probsum)
{
  __shared__ __align__(16) unsigned short wlds[3 * 8192];   // 48KB ring
  __shared__ float bLds[1160];  // [0,256) rb1 | [256,384) rb2 | [384,1152) rW3 | [1152,1158) rb3
  __shared__ float probsLds[768];
  __shared__ float psum[8];
  __shared__ int lcnt[8], gbase[8];

  int tid = threadIdx.x;
  int lane = tid & 63;
  int w = tid >> 6;            // 8 waves
  int col = lane & 15;
  int hi = lane >> 4;
  int tok0 = blockIdx.x * 128;
  int myTok = tok0 + w * 16 + col;

  if (tid < 256) bLds[tid] = rb1[tid];
  else if (tid < 384) bLds[tid] = rb2[tid - 256];
  for (int i = tid; i < 768; i += 512) bLds[384 + i] = rW3[i];
  if (tid < 6) bLds[1152 + tid] = rb3[tid];
  if (tid < 8) { psum[tid] = 0.f; lcnt[tid] = 0; }

  // X -> 3-way split B-frags (k = ks*32 + hi*8 + j)
  short8v xf0[4], xf1[4], xf2[4];
  {
    const float* px = x + (size_t)myTok * 128 + hi * 8;
    #pragma unroll
    for (int ks = 0; ks < 4; ++ks) {
      f32x4 lo = *(const f32x4*)(px + ks * 32);
      f32x4 hv = *(const f32x4*)(px + ks * 32 + 4);
      #pragma unroll
      for (int j = 0; j < 8; ++j) {
        float v = (j < 4) ? lo[j & 3] : hv[j & 3];
        unsigned short b0 = f2bf(v);
        float r1 = v - bf2f(b0);
        unsigned short b1 = f2bf(r1);
        float r2 = r1 - bf2f(b1);
        xf0[ks][j] = (short)b0;
        xf1[ks][j] = (short)b1;
        xf2[ks][j] = (short)f2bf(r2);
      }
    }
  }
  __syncthreads();   // bLds + lcnt ready

  RSTAGE(0);
  RSTAGE(1);

  // ---- L1: rW1(3-part) @ X(3-part) -> acc16 (units 0..255) ----
  f32x4 acc16[16] = {};
  #pragma unroll
  for (int c = 0; c < 4; ++c) {
    RPIPE(3 * c, 2);       // w0 chunk: x0, x1, x2
    #pragma unroll
    for (int ks = 0; ks < 4; ++ks)
      #pragma unroll
      for (int u = 0; u < 4; ++u) {
        short8v wf = FRAG(3 * c, u * 4 + ks);
        int t = 4 * c + u;
        acc16[t] = MM16(wf, xf0[ks], acc16[t]);
        acc16[t] = MM16(wf, xf1[ks], acc16[t]);
        acc16[t] = MM16(wf, xf2[ks], acc16[t]);
      }
    RPIPE(3 * c + 1, 2);   // w1 chunk: x0, x1
    #pragma unroll
    for (int ks = 0; ks < 4; ++ks)
      #pragma unroll
      for (int u = 0; u < 4; ++u) {
        short8v wf = FRAG(3 * c + 1, u * 4 + ks);
        int t = 4 * c + u;
        acc16[t] = MM16(wf, xf0[ks], acc16[t]);
        acc16[t] = MM16(wf, xf1[ks], acc16[t]);
      }
    RPIPE(3 * c + 2, 2);   // w2 chunk: x0
    #pragma unroll
    for (int ks = 0; ks < 4; ++ks)
      #pragma unroll
      for (int u = 0; u < 4; ++u) {
        short8v wf = FRAG(3 * c + 2, u * 4 + ks);
        int t = 4 * c + u;
        acc16[t] = MM16(wf, xf0[ks], acc16[t]);
      }
  }

  // h1 = gelu(acc16 + rb1) -> 2-way split frags
  short8v h0B[8], h1B[8];
  #pragma unroll
  for (int pr = 0; pr < 8; ++pr)
    cvt16s(acc16[2 * pr], acc16[2 * pr + 1], bLds + 32 * pr, hi, h0B[pr], h1B[pr]);

  // ---- L2: rW2(3-part) @ h1(2-part) -> acc2 (units 0..127) ----
  f32x4 acc2[8] = {};
  #pragma unroll
  for (int d = 0; d < 4; ++d) {
    RPIPE(12 + 3 * d, 2);      // w0: h0, h1
    #pragma unroll
    for (int ks = 0; ks < 8; ++ks)
      #pragma unroll
      for (int u = 0; u < 2; ++u) {
        short8v wf = FRAG(12 + 3 * d, u * 8 + ks);
        int t = 2 * d + u;
        acc2[t] = MM16(wf, h0B[ks], acc2[t]);
        acc2[t] = MM16(wf, h1B[ks], acc2[t]);
      }
    RPIPE(12 + 3 * d + 1, 2);  // w1: h0, h1
    #pragma unroll
    for (int ks = 0; ks < 8; ++ks)
      #pragma unroll
      for (int u = 0; u < 2; ++u) {
        short8v wf = FRAG(12 + 3 * d + 1, u * 8 + ks);
        int t = 2 * d + u;
        acc2[t] = MM16(wf, h0B[ks], acc2[t]);
        acc2[t] = MM16(wf, h1B[ks], acc2[t]);
      }
    if (d < 3) { RPIPE(12 + 3 * d + 2, 2); }
    else       { RPIPE(23, 0); }
    #pragma unroll
    for (int ks = 0; ks < 8; ++ks)
      #pragma unroll
      for (int u = 0; u < 2; ++u) {
        short8v wf = FRAG(12 + 3 * d + 2, u * 8 + ks);
        int t = 2 * d + u;
        acc2[t] = MM16(wf, h0B[ks], acc2[t]);
      }
  }

  // ---- logits: h2 = gelu(acc2 + rb2); partial dot rW3; reduce over hi ----
  float pl[6] = {0.f, 0.f, 0.f, 0.f, 0.f, 0.f};
  #pragma unroll
  for (int t = 0; t < 8; ++t)
    #pragma unroll
    for (int r = 0; r < 4; ++r) {
      int unit = t * 16 + 4 * hi + r;
      float h2 = geluf(acc2[t][r] + bLds[256 + unit]);
      #pragma unroll
      for (int e = 0; e < 6; ++e)
        pl[e] = fmaf(h2, bLds[384 + unit * 6 + e], pl[e]);
    }
  #pragma unroll
  for (int e = 0; e < 6; ++e) {
    pl[e] += __shfl_xor(pl[e], 16);
    pl[e] += __shfl_xor(pl[e], 32);
  }

  // ---- softmax / top-2 / bucketing (lanes hi==0 own one token each) ----
  int i1 = 0, i2 = 0, lp1 = 0, lp2 = 0;
  float ww1 = 0.f, ww2 = 0.f;
  if (hi == 0) {
    float l0[6];
    #pragma unroll
    for (int e = 0; e < 6; ++e) l0[e] = pl[e] + bLds[1152 + e];
    float m = l0[0];
    #pragma unroll
    for (int e = 1; e < 6; ++e) m = fmaxf(m, l0[e]);
    float pe[6]; float ssum = 0.f;
    #pragma unroll
    for (int e = 0; e < 6; ++e) { pe[e] = expf(l0[e] - m); ssum += pe[e]; }
    float inv = 1.f / ssum;
    int lrow = w * 16 + col;
    #pragma unroll
    for (int e = 0; e < 6; ++e) {
      float prb = pe[e] * inv;
      probsLds[lrow * 6 + e] = prb;
      atomicAdd(&psum[e], prb);
    }
    float v1 = l0[0]; i1 = 0; float v2 = -1e30f; i2 = -1;
    #pragma unroll
    for (int e = 1; e < 6; ++e) {
      float v = l0[e];
      if (v > v1) { v2 = v1; i2 = i1; v1 = v; i1 = e; }
      else if (v > v2) { v2 = v; i2 = e; }
    }
    float e2 = expf(v2 - v1);
    float den = 1.f / (1.f + e2);
    ww1 = den; ww2 = e2 * den;
    lp1 = atomicAdd(&lcnt[i1], 1);
    lp2 = atomicAdd(&lcnt[i2], 1);
  }
  __syncthreads();
  if (tid < 6) gbase[tid] = atomicAdd(&cnt[tid], lcnt[tid]);
  __syncthreads();
  if (hi == 0) {
    int g1 = gbase[i1] + lp1, g2 = gbase[i2] + lp2;
    pairTok[i1 * N_TOK + g1] = myTok; pairW[i1 * N_TOK + g1] = ww1;
    pairTok[i2 * N_TOK + g2] = myTok; pairW[i2 * N_TOK + g2] = ww2;
    pairIdx[2 * myTok]     = i1 * N_TOK + g1;
    pairIdx[2 * myTok + 1] = i2 * N_TOK + g2;
  }
  if (tid < 6) atomicAdd(&probsum[tid], psum[tid]);
  for (int i = tid; i < 768; i += 512)
    probs_out[(size_t)tok0 * 6 + i] = probsLds[i];
}

// ---------------- aux loss + csum ----------------
__global__ void aux_kernel(const float* __restrict__ probsum, const int* __restrict__ cnt,
                           int* __restrict__ csum, float* __restrict__ auxout)
{
  if (threadIdx.x == 0 && blockIdx.x == 0) {
    int s = 0;
    for (int e = 0; e < 6; ++e) { csum[e] = s; s += cnt[e]; }
    float ent = 0.f, l2 = 0.f;
    for (int e = 0; e < 6; ++e) {
      float avg = probsum[e] / (float)N_TOK;
      ent -= avg * logf(avg + 1e-8f);
      float d = avg - (1.0f / 6.0f);
      l2 += d * d;
    }
    l2 *= (1.0f / 6.0f);
    auxout[0] = -ent * 0.01f + 0.01f * l2;
  }
}

// ---------------- expert kernel (R9, verified) ----------------
#define STAGE(s) do { \
    const unsigned short* gsrc_ = eblob + (s) * 8192 + w * 1024 + lane * 8; \
    unsigned short* ldst_ = &wlds[((s) % 3) * 8192 + w * 1024]; \
    _Pragma("unroll") \
    for (int i_ = 0; i_ < 2; ++i_) \
      __builtin_amdgcn_global_load_lds((gl_byte*)(gsrc_ + i_ * 512), (lds_byte*)(ldst_ + i_ * 512), 16, 0, 0); \
  } while (0)

#define PIPE(s, nw) do { \
    asm volatile("s_waitcnt vmcnt(" #nw ")" ::: "memory"); \
    __builtin_amdgcn_sched_barrier(0); \
    __builtin_amdgcn_s_barrier(); \
    __builtin_amdgcn_sched_barrier(0); \
    if ((s) + 2 < NSTAGE) STAGE((s) + 2); \
  } while (0)

template<int OUTMODE>   // 0 = scratch pair partials, 1 = atomicAdd into d_out
__global__ __launch_bounds__(512) void expert_kernel(
    const float* __restrict__ x,
    const unsigned short* __restrict__ blob,
    const float* __restrict__ tb1, const float* __restrict__ tb2, const float* __restrict__ tb3,
    const float* __restrict__ sb1, const float* __restrict__ sb2,
    const float* __restrict__ sW3, const float* __restrict__ sb3,
    const int* __restrict__ pairTok, const float* __restrict__ pairW,
    const int* __restrict__ cnt, const int* __restrict__ csum,
    float* __restrict__ traj_out, float* __restrict__ score_out,
    unsigned short* __restrict__ trajP, float* __restrict__ scoreP)
{
  int e = blockIdx.y;
  int base = blockIdx.x * 128;
  int count = cnt[e];
  if (base >= count) return;

  __shared__ __align__(16) unsigned short wlds[3 * 8192];   // 48KB ring
  __shared__ float bLds[896];
  __shared__ int   toksLds[128];
  __shared__ float gwsLds[128];

  int tid = threadIdx.x;
  int lane = tid & 63;
  int w = tid >> 6;            // 8 waves
  int col = lane & 15;
  int hi = lane >> 4;
  const unsigned short* eblob = blob + (size_t)e * PER_E;
  int slotbase = csum[e] + base;

  if (tid < 128) {
    int idx = e * N_TOK + base + ((base + tid < count) ? tid : 0);
    toksLds[tid] = pairTok[idx];
    gwsLds[tid] = (base + tid < count) ? pairW[idx] : 0.f;
  }
  if (tid < 128) bLds[tid] = sb1[e * 128 + tid];
  if (tid < 64)  bLds[128 + tid] = sb2[e * 64 + tid];
  if (tid < 64)  bLds[192 + tid] = sW3[e * 64 + tid];
  if (tid < 256) { bLds[256 + tid] = tb1[e * 256 + tid]; bLds[512 + tid] = tb2[e * 256 + tid]; }
  if (tid < 120) bLds[768 + tid] = tb3[e * 120 + tid];
  __syncthreads();

  int row = w * 16 + col;
  int tok = toksLds[row];
  bool valid = (base + row < count);
  float gw = gwsLds[row];

  short8v xf[4];
  {
    const float* px = x + (size_t)tok * 128 + hi * 8;
    #pragma unroll
    for (int ks = 0; ks < 4; ++ks) {
      f32x4 lo = *(const f32x4*)(px + ks * 32);
      f32x4 hv = *(const f32x4*)(px + ks * 32 + 4);
      short8v t;
      #pragma unroll
      for (int j = 0; j < 4; ++j) { t[j] = (short)f2bf(lo[j]); t[4 + j] = (short)f2bf(hv[j]); }
      xf[ks] = t;
    }
  }

  STAGE(0);
  STAGE(1);

  short8v sB[4];
  {
    f32x4 a[4] = {};
    PIPE(0, 2);
    #pragma unroll
    for (int f = 0; f < 16; ++f)
      a[f >> 2] = MM16(FRAG(0, f), xf[f & 3], a[f >> 2]);
    cvt16(a[0], a[1], bLds + 0,  hi, sB[0]);  cvt16(a[2], a[3], bLds + 32, hi, sB[1]);
    f32x4 b[4] = {};
    PIPE(1, 2);
    #pragma unroll
    for (int f = 0; f < 16; ++f)
      b[f >> 2] = MM16(FRAG(1, f), xf[f & 3], b[f >> 2]);
    cvt16(b[0], b[1], bLds + 64, hi, sB[2]);  cvt16(b[2], b[3], bLds + 96, hi, sB[3]);
  }

  float p0 = 0.f;
  {
    f32x4 q[4] = {};
    PIPE(2, 2);
    #pragma unroll
    for (int f = 0; f < 16; ++f)
      q[f >> 2] = MM16(FRAG(2, f), sB[f & 3], q[f >> 2]);
    #pragma unroll
    for (int t = 0; t < 4; ++t)
      #pragma unroll
      for (int r = 0; r < 4; ++r) {
        int unit = t * 16 + 4 * hi + r;
        p0 += geluf(q[t][r] + bLds[128 + unit]) * bLds[192 + unit];
      }
    p0 += __shfl_xor(p0, 16); p0 += __shfl_xor(p0, 32);
  }

  short8v h1B[8];
  #define T1S(t, S) { \
    f32x4 a[4] = {}; \
    PIPE(S, 2); \
    _Pragma("unroll") \
    for (int f = 0; f < 16; ++f) \
      a[f >> 2] = MM16(FRAG(S, f), xf[f & 3], a[f >> 2]); \
    cvt16(a[0], a[1], bLds + 256 + (t) * 64,      hi, h1B[2 * (t)]); \
    cvt16(a[2], a[3], bLds + 256 + (t) * 64 + 32, hi, h1B[2 * (t) + 1]); \
  }
  T1S(0, 3) T1S(1, 4) T1S(2, 5) T1S(3, 6)

  short8v h2B[4];
  #define T2S(s, S, BOFF) { \
    f32x4 u[2] = {}; \
    PIPE(S, 2); \
    _Pragma("unroll") \
    for (int f = 0; f < 16; ++f) \
      u[f >> 3] = MM16(FRAG(S, f), h1B[f & 7], u[f >> 3]); \
    cvt16(u[0], u[1], bLds + 512 + (BOFF) + 32 * (s), hi, h2B[s]); \
  }

  f32x4 wacc[8] = {};
  #define T3S(s, S, NW) { \
    PIPE(S, NW); \
    _Pragma("unroll") \
    for (int f = 0; f < 16; ++f) \
      wacc[f >> 1] = MM16(FRAG(S, f), h2B[2 * (s) + (f & 1)], wacc[f >> 1]); \
  }

  T2S(0, 7, 0) T2S(1, 8, 0) T2S(2, 9, 0) T2S(3, 10, 0)
  T3S(0, 11, 2) T3S(1, 12, 2)
  T2S(0, 13, 128) T2S(1, 14, 128) T2S(2, 15, 128) T2S(3, 16, 128)
  T3S(0, 17, 2) T3S(1, 18, 0)

  if (hi == 0 && valid) {
    float v = gw * (p0 + sb3[e]);
    if (OUTMODE == 0) scoreP[slotbase + row] = v; else atomicAdd(&score_out[tok], v);
  }
  if (valid) {
    if (OUTMODE == 0) {
      unsigned short* dst = trajP + (size_t)(slotbase + row) * 120;
      #pragma unroll
      for (int t = 0; t < 8; ++t)
        #pragma unroll
        for (int r = 0; r < 4; r += 2) {
          int unit = t * 16 + 4 * hi + r;
          if (unit + 1 < 120) {
            float a0 = gw * (wacc[t][r] + bLds[768 + unit]);
            float a1 = gw * (wacc[t][r + 1] + bLds[768 + unit + 1]);
            *(unsigned int*)(dst + unit) = (unsigned)f2bf(a0) | ((unsigned)f2bf(a1) << 16);
          }
        }
    } else {
      float* dst = traj_out + (size_t)tok * 120;
      #pragma unroll
      for (int t = 0; t < 8; ++t)
        #pragma unroll
        for (int r = 0; r < 4; ++r) {
          int unit = t * 16 + 4 * hi + r;
          if (unit < 120) atomicAdd(&dst[unit], gw * (wacc[t][r] + bLds[768 + unit]));
        }
    }
  }
}

// ---------------- combine ----------------
__global__ __launch_bounds__(256) void combine_kernel(
    const int* __restrict__ pairIdx, const int* __restrict__ csum,
    const unsigned short* __restrict__ trajP, const float* __restrict__ scoreP,
    float* __restrict__ traj_out, float* __restrict__ score_out)
{
  int t = blockIdx.x * 256 + threadIdx.x;
  if (t >= N_TOK) return;
  int p0 = pairIdx[2 * t], p1 = pairIdx[2 * t + 1];
  int e0 = p0 / N_TOK, e1 = p1 / N_TOK;
  size_t s0 = (size_t)csum[e0] + (p0 - e0 * N_TOK);
  size_t s1 = (size_t)csum[e1] + (p1 - e1 * N_TOK);
  const unsigned short* r0 = trajP + s0 * 120;
  const unsigned short* r1 = trajP + s1 * 120;
  float* o = traj_out + (size_t)t * 120;
  #pragma unroll 6
  for (int i = 0; i < 30; ++i) {
    u16x4 a = *(const u16x4*)(r0 + i * 4);
    u16x4 b = *(const u16x4*)(r1 + i * 4);
    f32x4 v;
    #pragma unroll
    for (int jj = 0; jj < 4; ++jj) v[jj] = bf2f(a[jj]) + bf2f(b[jj]);
    *(f32x4*)(o + i * 4) = v;
  }
  score_out[t] = scoreP[s0] + scoreP[s1];
}

extern "C" void kernel_launch(void* const* d_in, const int* in_sizes, int n_in,
                              void* d_out, int out_size, void* d_ws, size_t ws_size,
                              hipStream_t stream) {
  (void)in_sizes; (void)n_in; (void)out_size;
  const float* x   = (const float*)d_in[0];
  const float* rW1 = (const float*)d_in[1];
  const float* rb1 = (const float*)d_in[2];
  const float* rW2 = (const float*)d_in[3];
  const float* rb2 = (const float*)d_in[4];
  const float* rW3 = (const float*)d_in[5];
  const float* rb3 = (const float*)d_in[6];
  const float* tW1 = (const float*)d_in[7];
  const float* tb1 = (const float*)d_in[8];
  const float* tW2 = (const float*)d_in[9];
  const float* tb2 = (const float*)d_in[10];
  const float* tW3 = (const float*)d_in[11];
  const float* tb3 = (const float*)d_in[12];
  const float* sW1 = (const float*)d_in[13];
  const float* sb1 = (const float*)d_in[14];
  const float* sW2 = (const float*)d_in[15];
  const float* sb2 = (const float*)d_in[16];
  const float* sW3 = (const float*)d_in[17];
  const float* sb3 = (const float*)d_in[18];
  float* out = (float*)d_out;

  // workspace carve (bytes)
  char* wsb = (char*)d_ws;
  int*   cnt     = (int*)(wsb + 0);
  float* probsum = (float*)(wsb + 32);
  int*   csum    = (int*)(wsb + 64);
  int*   pairTok = (int*)(wsb + 96);
  float* pairW   = (float*)(wsb + 96 + (size_t)6 * N_TOK * 4);
  int*   pairIdx = (int*)(wsb + 96 + (size_t)12 * N_TOK * 4);
  float* scoreP  = (float*)(wsb + 96 + (size_t)14 * N_TOK * 4);
  unsigned short* blob  = (unsigned short*)(wsb + 96 + (size_t)16 * N_TOK * 4);
  unsigned short* rblob = (unsigned short*)(wsb + 96 + (size_t)16 * N_TOK * 4 + (size_t)6 * PER_E * 2);
  unsigned short* trajP = (unsigned short*)(wsb + 96 + (size_t)16 * N_TOK * 4 + (size_t)6 * PER_E * 2
                                            + (size_t)RSTAGES * 8192 * 2);
  size_t need = 96 + (size_t)16 * N_TOK * 4 + (size_t)6 * PER_E * 2 + (size_t)RSTAGES * 8192 * 2
              + (size_t)2 * N_TOK * 120 * 2;
  bool scratch = ws_size >= need;

  hipMemsetAsync(wsb, 0, 96, stream);
  if (!scratch) hipMemsetAsync(d_out, 0, (size_t)(N_TOK * 121) * 4, stream);

  prep_weights<<<(6 * PER_E) / 256, 256, 0, stream>>>(tW1, tW2, tW3, sW1, sW2, blob);
  prep_router<<<(RSTAGES * 8192) / 256, 256, 0, stream>>>(rW1, rW2, rblob);
  router_mfma<<<N_TOK / 128, 512, 0, stream>>>(x, rblob, rb1, rb2, rW3, rb3,
                                               out + PROB_OFF, pairTok, pairW, pairIdx, cnt, probsum);
  aux_kernel<<<1, 64, 0, stream>>>(probsum, cnt, csum, out + AUX_OFF);
  if (scratch) {
    expert_kernel<0><<<dim3(N_TOK / 128, 6), 512, 0, stream>>>(
        x, blob, tb1, tb2, tb3, sb1, sb2, sW3, sb3, pairTok, pairW, cnt, csum,
        out + TRAJ_OFF, out + SCORE_OFF, trajP, scoreP);
    combine_kernel<<<N_TOK / 256, 256, 0, stream>>>(pairIdx, csum, trajP, scoreP,
                                                    out + TRAJ_OFF, out + SCORE_OFF);
  } else {
    expert_kernel<1><<<dim3(N_TOK / 128, 6), 512, 0, stream>>>(
        x, blob, tb1, tb2, tb3, sb1, sb2, sW3, sb3, pairTok, pairW, cnt, csum,
        out + TRAJ_OFF, out + SCORE_OFF, trajP, scoreP);
  }
}

// Round 11
// 174.121 us; speedup vs baseline: 3.8747x; 1.0687x over previous
//
#include <hip/hip_runtime.h>

#define N_TOK 49152
#define PER_E 155648      // expert blob: 19 stages * 8192 bf16 elems per expert
#define NSTAGE 19
#define RSTAGES 24        // router blob: 24 stages * 8192 bf16 elems

// d_out float offsets
#define TRAJ_OFF 0
#define SCORE_OFF 5898240
#define AUX_OFF  5947392
#define PROB_OFF 5947393

typedef __attribute__((ext_vector_type(8))) short short8v;
typedef __attribute__((ext_vector_type(4))) float f32x4;
typedef __attribute__((ext_vector_type(4))) unsigned short u16x4;

typedef __attribute__((address_space(3))) unsigned char lds_byte;
typedef __attribute__((address_space(1))) const unsigned char gl_byte;

__device__ __forceinline__ unsigned short f2bf(float f) {
  unsigned int u = __float_as_uint(f);
  u = (u + 0x7FFFu + ((u >> 16) & 1u)) >> 16;
  return (unsigned short)u;
}
__device__ __forceinline__ float bf2f(unsigned short h) {
  return __uint_as_float(((unsigned int)h) << 16);
}
// branch-free erf (A&S 7.1.26, abs err <1.5e-7) -> exact-gelu replacement
__device__ __forceinline__ float geluf(float v) {
  float x = v * 0.70710678118654752f;
  float ax = fabsf(x);
  float t = __builtin_amdgcn_rcpf(fmaf(0.3275911f, ax, 1.0f));
  float p = t * fmaf(t, fmaf(t, fmaf(t, fmaf(t, 1.061405429f, -1.453152027f),
                                     1.421413741f), -0.284496736f), 0.254829592f);
  float er = 1.0f - p * __expf(-ax * ax);
  er = copysignf(er, x);
  return 0.5f * v * (1.0f + er);
}

// ---------------- expert weight prep (verified R7-R10) ----------------
__global__ __launch_bounds__(256) void prep_weights(
    const float* __restrict__ tW1, const float* __restrict__ tW2, const float* __restrict__ tW3,
    const float* __restrict__ sW1, const float* __restrict__ sW2,
    unsigned short* __restrict__ blob)
{
  int id = blockIdx.x * 256 + threadIdx.x;
  if (id >= 6 * PER_E) return;
  int e = id / PER_E;
  int r = id - e * PER_E;
  int p = r >> 13;
  int q = r & 8191;
  int f = q >> 9;
  int l = (q >> 3) & 63;
  int j = q & 7;
  int hi = l >> 4, rl = l & 15;
  const float* src; int N, tile, ks; bool perm;
  if (p < 2)       { src = sW1 + e * 16384; N = 128; tile = 4 * p + (f >> 2);        ks = f & 3; perm = false; }
  else if (p == 2) { src = sW2 + e * 8192;  N = 64;  tile = f >> 2;                  ks = f & 3; perm = true;  }
  else if (p < 7)  { src = tW1 + e * 32768; N = 256; tile = 4 * (p - 3) + (f >> 2);  ks = f & 3; perm = false; }
  else if (p < 11) { src = tW2 + e * 65536; N = 256; tile = 2 * (p - 7) + (f >> 3);  ks = f & 7; perm = true;  }
  else if (p < 13) { src = tW3 + e * 30720; N = 120; tile = f >> 1;  ks = 2 * (p - 11) + (f & 1); perm = true; }
  else if (p < 17) { src = tW2 + e * 65536; N = 256; tile = 8 + 2 * (p - 13) + (f >> 3); ks = f & 7; perm = true; }
  else             { src = tW3 + e * 30720; N = 120; tile = f >> 1;  ks = 4 + 2 * (p - 17) + (f & 1); perm = true; }
  int k = ks * 32 + (perm ? (16 * (j >> 2) + 4 * hi + (j & 3)) : (8 * hi + j));
  int unit = tile * 16 + rl;
  blob[id] = f2bf(unit < N ? src[k * N + unit] : 0.0f);
}

// ---------------- router weight prep: 3-way bf16 split (verified R10) ----------------
__global__ __launch_bounds__(256) void prep_router(
    const float* __restrict__ rW1, const float* __restrict__ rW2,
    unsigned short* __restrict__ rblob)
{
  int id = blockIdx.x * 256 + threadIdx.x;
  if (id >= RSTAGES * 8192) return;
  int p = id >> 13;
  int q = id & 8191;
  int f = q >> 9;
  int l = (q >> 3) & 63;
  int j = q & 7;
  int hi = l >> 4, rl = l & 15;
  const float* src; int N, tile, ks, part; bool perm;
  if (p < 12) { int c = p / 3; part = p % 3; src = rW1; N = 256; tile = 4 * c + (f >> 2); ks = f & 3; perm = false; }
  else        { int c = (p - 12) / 3; part = (p - 12) % 3; src = rW2; N = 128; tile = 2 * c + (f >> 3); ks = f & 7; perm = true; }
  int k = ks * 32 + (perm ? (16 * (j >> 2) + 4 * hi + (j & 3)) : (8 * hi + j));
  int unit = tile * 16 + rl;
  float v = (unit < N) ? src[k * N + unit] : 0.0f;
  unsigned short b0 = f2bf(v);
  float r1 = v - bf2f(b0);
  unsigned short b1 = f2bf(r1);
  float r2 = r1 - bf2f(b1);
  unsigned short b2 = f2bf(r2);
  rblob[id] = (part == 0) ? b0 : ((part == 1) ? b1 : b2);
}

// ---------------- shared MFMA helpers ----------------
__device__ __forceinline__ f32x4 MM16(short8v a, short8v b, f32x4 c) {
  return __builtin_amdgcn_mfma_f32_16x16x32_bf16(a, b, c, 0, 0, 0);
}
__device__ __forceinline__ void cvt16(f32x4 aE, f32x4 aO, const float* bp, int hi, short8v& fr) {
  #pragma unroll
  for (int j = 0; j < 8; ++j) {
    float v = (j < 4) ? aE[j & 3] : aO[j & 3];
    int unit = 16 * (j >> 2) + 4 * hi + (j & 3);
    fr[j] = (short)f2bf(geluf(v + bp[unit]));
  }
}
__device__ __forceinline__ void cvt16s(f32x4 aE, f32x4 aO, const float* bp, int hi,
                                       short8v& f0, short8v& f1) {
  #pragma unroll
  for (int j = 0; j < 8; ++j) {
    float v = (j < 4) ? aE[j & 3] : aO[j & 3];
    int unit = 16 * (j >> 2) + 4 * hi + (j & 3);
    float g = geluf(v + bp[unit]);
    unsigned short b0 = f2bf(g);
    f0[j] = (short)b0;
    f1[j] = (short)f2bf(g - bf2f(b0));
  }
}

#define FRAG(s, f) (*(const short8v*)(&wlds[((s) % 3) * 8192 + (f) * 512 + lane * 8]))

// ---------------- MFMA router: split-bf16 fp32-grade logits ----------------
#define RSTAGE(s) do { \
    const unsigned short* gsrc_ = rblob + (s) * 8192 + w * 1024 + lane * 8; \
    unsigned short* ldst_ = &wlds[((s) % 3) * 8192 + w * 1024]; \
    _Pragma("unroll") \
    for (int i_ = 0; i_ < 2; ++i_) \
      __builtin_amdgcn_global_load_lds((gl_byte*)(gsrc_ + i_ * 512), (lds_byte*)(ldst_ + i_ * 512), 16, 0, 0); \
  } while (0)

#define RPIPE(s, nw) do { \
    asm volatile("s_waitcnt vmcnt(" #nw ")" ::: "memory"); \
    __builtin_amdgcn_sched_barrier(0); \
    __builtin_amdgcn_s_barrier(); \
    __builtin_amdgcn_sched_barrier(0); \
    if ((s) + 2 < RSTAGES) RSTAGE((s) + 2); \
  } while (0)

__global__ __launch_bounds__(512, 4) void router_mfma(
    const float* __restrict__ x, const unsigned short* __restrict__ rblob,
    const float* __restrict__ rb1, const float* __restrict__ rb2,
    const float* __restrict__ rW3, const float* __restrict__ rb3,
    float* __restrict__ probs_out,
    int* __restrict__ pairTok, float* __restrict__ pairW, int* __restrict__ pairIdx,
    int* __restrict__ cnt, float* __restrict__ probsum)
{
  __shared__ __align__(16) unsigned short wlds[3 * 8192];   // 48KB ring
  __shared__ float bLds[1160];  // [0,256) rb1 | [256,384) rb2 | [384,1152) rW3 | [1152,1158) rb3
  __shared__ float probsLds[768];
  __shared__ float psum[8];
  __shared__ int lcnt[8], gbase[8];

  int tid = threadIdx.x;
  int lane = tid & 63;
  int w = tid >> 6;            // 8 waves
  int col = lane & 15;
  int hi = lane >> 4;
  int tok0 = blockIdx.x * 128;
  int myTok = tok0 + w * 16 + col;

  if (tid < 256) bLds[tid] = rb1[tid];
  else if (tid < 384) bLds[tid] = rb2[tid - 256];
  for (int i = tid; i < 768; i += 512) bLds[384 + i] = rW3[i];
  if (tid < 6) bLds[1152 + tid] = rb3[tid];
  if (tid < 8) { psum[tid] = 0.f; lcnt[tid] = 0; }

  // X -> 3-way split B-frags (k = ks*32 + hi*8 + j)
  short8v xf0[4], xf1[4], xf2[4];
  {
    const float* px = x + (size_t)myTok * 128 + hi * 8;
    #pragma unroll
    for (int ks = 0; ks < 4; ++ks) {
      f32x4 lo = *(const f32x4*)(px + ks * 32);
      f32x4 hv = *(const f32x4*)(px + ks * 32 + 4);
      #pragma unroll
      for (int j = 0; j < 8; ++j) {
        float v = (j < 4) ? lo[j & 3] : hv[j & 3];
        unsigned short b0 = f2bf(v);
        float r1 = v - bf2f(b0);
        unsigned short b1 = f2bf(r1);
        float r2 = r1 - bf2f(b1);
        xf0[ks][j] = (short)b0;
        xf1[ks][j] = (short)b1;
        xf2[ks][j] = (short)f2bf(r2);
      }
    }
  }
  __syncthreads();   // bLds + lcnt ready

  RSTAGE(0);
  RSTAGE(1);

  // ---- L1: rW1(3-part) @ X(3-part); per-chunk acc (16 regs) -> h frags immediately ----
  short8v h0B[8], h1B[8];
  #pragma unroll
  for (int c = 0; c < 4; ++c) {
    f32x4 acc[4] = {};
    RPIPE(3 * c, 2);       // w0 chunk: x0, x1, x2
    #pragma unroll
    for (int ks = 0; ks < 4; ++ks)
      #pragma unroll
      for (int u = 0; u < 4; ++u) {
        short8v wf = FRAG(3 * c, u * 4 + ks);
        acc[u] = MM16(wf, xf0[ks], acc[u]);
        acc[u] = MM16(wf, xf1[ks], acc[u]);
        acc[u] = MM16(wf, xf2[ks], acc[u]);
      }
    RPIPE(3 * c + 1, 2);   // w1 chunk: x0, x1
    #pragma unroll
    for (int ks = 0; ks < 4; ++ks)
      #pragma unroll
      for (int u = 0; u < 4; ++u) {
        short8v wf = FRAG(3 * c + 1, u * 4 + ks);
        acc[u] = MM16(wf, xf0[ks], acc[u]);
        acc[u] = MM16(wf, xf1[ks], acc[u]);
      }
    RPIPE(3 * c + 2, 2);   // w2 chunk: x0
    #pragma unroll
    for (int ks = 0; ks < 4; ++ks)
      #pragma unroll
      for (int u = 0; u < 4; ++u) {
        short8v wf = FRAG(3 * c + 2, u * 4 + ks);
        acc[u] = MM16(wf, xf0[ks], acc[u]);
      }
    // tiles 4c..4c+3 -> 32-unit blocks 2c, 2c+1 (units 64c..64c+63)
    cvt16s(acc[0], acc[1], bLds + 32 * (2 * c),     hi, h0B[2 * c],     h1B[2 * c]);
    cvt16s(acc[2], acc[3], bLds + 32 * (2 * c + 1), hi, h0B[2 * c + 1], h1B[2 * c + 1]);
  }

  // ---- L2: rW2(3-part) @ h1(2-part) -> acc2 (units 0..127) ----
  f32x4 acc2[8] = {};
  #pragma unroll
  for (int d = 0; d < 4; ++d) {
    RPIPE(12 + 3 * d, 2);      // w0: h0, h1
    #pragma unroll
    for (int ks = 0; ks < 8; ++ks)
      #pragma unroll
      for (int u = 0; u < 2; ++u) {
        short8v wf = FRAG(12 + 3 * d, u * 8 + ks);
        int t = 2 * d + u;
        acc2[t] = MM16(wf, h0B[ks], acc2[t]);
        acc2[t] = MM16(wf, h1B[ks], acc2[t]);
      }
    RPIPE(12 + 3 * d + 1, 2);  // w1: h0, h1
    #pragma unroll
    for (int ks = 0; ks < 8; ++ks)
      #pragma unroll
      for (int u = 0; u < 2; ++u) {
        short8v wf = FRAG(12 + 3 * d + 1, u * 8 + ks);
        int t = 2 * d + u;
        acc2[t] = MM16(wf, h0B[ks], acc2[t]);
        acc2[t] = MM16(wf, h1B[ks], acc2[t]);
      }
    if (d < 3) { RPIPE(12 + 3 * d + 2, 2); }
    else       { RPIPE(23, 0); }
    #pragma unroll
    for (int ks = 0; ks < 8; ++ks)
      #pragma unroll
      for (int u = 0; u < 2; ++u) {
        short8v wf = FRAG(12 + 3 * d + 2, u * 8 + ks);
        int t = 2 * d + u;
        acc2[t] = MM16(wf, h0B[ks], acc2[t]);
      }
  }

  // ---- logits: h2 = gelu(acc2 + rb2); partial dot rW3; reduce over hi ----
  float pl[6] = {0.f, 0.f, 0.f, 0.f, 0.f, 0.f};
  #pragma unroll
  for (int t = 0; t < 8; ++t)
    #pragma unroll
    for (int r = 0; r < 4; ++r) {
      int unit = t * 16 + 4 * hi + r;
      float h2 = geluf(acc2[t][r] + bLds[256 + unit]);
      #pragma unroll
      for (int e = 0; e < 6; ++e)
        pl[e] = fmaf(h2, bLds[384 + unit * 6 + e], pl[e]);
    }
  #pragma unroll
  for (int e = 0; e < 6; ++e) {
    pl[e] += __shfl_xor(pl[e], 16);
    pl[e] += __shfl_xor(pl[e], 32);
  }

  // ---- softmax / top-2 / bucketing (lanes hi==0 own one token each) ----
  int i1 = 0, i2 = 0, lp1 = 0, lp2 = 0;
  float ww1 = 0.f, ww2 = 0.f;
  if (hi == 0) {
    float l0[6];
    #pragma unroll
    for (int e = 0; e < 6; ++e) l0[e] = pl[e] + bLds[1152 + e];
    float m = l0[0];
    #pragma unroll
    for (int e = 1; e < 6; ++e) m = fmaxf(m, l0[e]);
    float pe[6]; float ssum = 0.f;
    #pragma unroll
    for (int e = 0; e < 6; ++e) { pe[e] = expf(l0[e] - m); ssum += pe[e]; }
    float inv = 1.f / ssum;
    int lrow = w * 16 + col;
    #pragma unroll
    for (int e = 0; e < 6; ++e) {
      float prb = pe[e] * inv;
      probsLds[lrow * 6 + e] = prb;
      atomicAdd(&psum[e], prb);
    }
    float v1 = l0[0]; i1 = 0; float v2 = -1e30f; i2 = -1;
    #pragma unroll
    for (int e = 1; e < 6; ++e) {
      float v = l0[e];
      if (v > v1) { v2 = v1; i2 = i1; v1 = v; i1 = e; }
      else if (v > v2) { v2 = v; i2 = e; }
    }
    float e2 = expf(v2 - v1);
    float den = 1.f / (1.f + e2);
    ww1 = den; ww2 = e2 * den;
    lp1 = atomicAdd(&lcnt[i1], 1);
    lp2 = atomicAdd(&lcnt[i2], 1);
  }
  __syncthreads();
  if (tid < 6) gbase[tid] = atomicAdd(&cnt[tid], lcnt[tid]);
  __syncthreads();
  if (hi == 0) {
    int g1 = gbase[i1] + lp1, g2 = gbase[i2] + lp2;
    pairTok[i1 * N_TOK + g1] = myTok; pairW[i1 * N_TOK + g1] = ww1;
    pairTok[i2 * N_TOK + g2] = myTok; pairW[i2 * N_TOK + g2] = ww2;
    pairIdx[2 * myTok]     = i1 * N_TOK + g1;
    pairIdx[2 * myTok + 1] = i2 * N_TOK + g2;
  }
  if (tid < 6) atomicAdd(&probsum[tid], psum[tid]);
  for (int i = tid; i < 768; i += 512)
    probs_out[(size_t)tok0 * 6 + i] = probsLds[i];
}

// ---------------- aux loss + csum ----------------
__global__ void aux_kernel(const float* __restrict__ probsum, const int* __restrict__ cnt,
                           int* __restrict__ csum, float* __restrict__ auxout)
{
  if (threadIdx.x == 0 && blockIdx.x == 0) {
    int s = 0;
    for (int e = 0; e < 6; ++e) { csum[e] = s; s += cnt[e]; }
    float ent = 0.f, l2 = 0.f;
    for (int e = 0; e < 6; ++e) {
      float avg = probsum[e] / (float)N_TOK;
      ent -= avg * logf(avg + 1e-8f);
      float d = avg - (1.0f / 6.0f);
      l2 += d * d;
    }
    l2 *= (1.0f / 6.0f);
    auxout[0] = -ent * 0.01f + 0.01f * l2;
  }
}

// ---------------- expert kernel (R9 structure, VGPR budget pinned) ----------------
#define STAGE(s) do { \
    const unsigned short* gsrc_ = eblob + (s) * 8192 + w * 1024 + lane * 8; \
    unsigned short* ldst_ = &wlds[((s) % 3) * 8192 + w * 1024]; \
    _Pragma("unroll") \
    for (int i_ = 0; i_ < 2; ++i_) \
      __builtin_amdgcn_global_load_lds((gl_byte*)(gsrc_ + i_ * 512), (lds_byte*)(ldst_ + i_ * 512), 16, 0, 0); \
  } while (0)

#define PIPE(s, nw) do { \
    asm volatile("s_waitcnt vmcnt(" #nw ")" ::: "memory"); \
    __builtin_amdgcn_sched_barrier(0); \
    __builtin_amdgcn_s_barrier(); \
    __builtin_amdgcn_sched_barrier(0); \
    if ((s) + 2 < NSTAGE) STAGE((s) + 2); \
  } while (0)

template<int OUTMODE>   // 0 = scratch pair partials, 1 = atomicAdd into d_out
__global__ __launch_bounds__(512, 4) void expert_kernel(
    const float* __restrict__ x,
    const unsigned short* __restrict__ blob,
    const float* __restrict__ tb1, const float* __restrict__ tb2, const float* __restrict__ tb3,
    const float* __restrict__ sb1, const float* __restrict__ sb2,
    const float* __restrict__ sW3, const float* __restrict__ sb3,
    const int* __restrict__ pairTok, const float* __restrict__ pairW,
    const int* __restrict__ cnt, const int* __restrict__ csum,
    float* __restrict__ traj_out, float* __restrict__ score_out,
    unsigned short* __restrict__ trajP, float* __restrict__ scoreP)
{
  int e = blockIdx.y;
  int base = blockIdx.x * 128;
  int count = cnt[e];
  if (base >= count) return;

  __shared__ __align__(16) unsigned short wlds[3 * 8192];   // 48KB ring
  __shared__ float bLds[896];
  __shared__ int   toksLds[128];
  __shared__ float gwsLds[128];

  int tid = threadIdx.x;
  int lane = tid & 63;
  int w = tid >> 6;            // 8 waves
  int col = lane & 15;
  int hi = lane >> 4;
  const unsigned short* eblob = blob + (size_t)e * PER_E;
  int slotbase = csum[e] + base;

  if (tid < 128) {
    int idx = e * N_TOK + base + ((base + tid < count) ? tid : 0);
    toksLds[tid] = pairTok[idx];
    gwsLds[tid] = (base + tid < count) ? pairW[idx] : 0.f;
  }
  if (tid < 128) bLds[tid] = sb1[e * 128 + tid];
  if (tid < 64)  bLds[128 + tid] = sb2[e * 64 + tid];
  if (tid < 64)  bLds[192 + tid] = sW3[e * 64 + tid];
  if (tid < 256) { bLds[256 + tid] = tb1[e * 256 + tid]; bLds[512 + tid] = tb2[e * 256 + tid]; }
  if (tid < 120) bLds[768 + tid] = tb3[e * 120 + tid];
  __syncthreads();

  int row = w * 16 + col;
  int tok = toksLds[row];
  bool valid = (base + row < count);
  float gw = gwsLds[row];

  short8v xf[4];
  {
    const float* px = x + (size_t)tok * 128 + hi * 8;
    #pragma unroll
    for (int ks = 0; ks < 4; ++ks) {
      f32x4 lo = *(const f32x4*)(px + ks * 32);
      f32x4 hv = *(const f32x4*)(px + ks * 32 + 4);
      short8v t;
      #pragma unroll
      for (int j = 0; j < 4; ++j) { t[j] = (short)f2bf(lo[j]); t[4 + j] = (short)f2bf(hv[j]); }
      xf[ks] = t;
    }
  }

  STAGE(0);
  STAGE(1);

  short8v sB[4];
  {
    f32x4 a[4] = {};
    PIPE(0, 2);
    #pragma unroll
    for (int f = 0; f < 16; ++f)
      a[f >> 2] = MM16(FRAG(0, f), xf[f & 3], a[f >> 2]);
    cvt16(a[0], a[1], bLds + 0,  hi, sB[0]);  cvt16(a[2], a[3], bLds + 32, hi, sB[1]);
    f32x4 b[4] = {};
    PIPE(1, 2);
    #pragma unroll
    for (int f = 0; f < 16; ++f)
      b[f >> 2] = MM16(FRAG(1, f), xf[f & 3], b[f >> 2]);
    cvt16(b[0], b[1], bLds + 64, hi, sB[2]);  cvt16(b[2], b[3], bLds + 96, hi, sB[3]);
  }

  float p0 = 0.f;
  {
    f32x4 q[4] = {};
    PIPE(2, 2);
    #pragma unroll
    for (int f = 0; f < 16; ++f)
      q[f >> 2] = MM16(FRAG(2, f), sB[f & 3], q[f >> 2]);
    #pragma unroll
    for (int t = 0; t < 4; ++t)
      #pragma unroll
      for (int r = 0; r < 4; ++r) {
        int unit = t * 16 + 4 * hi + r;
        p0 += geluf(q[t][r] + bLds[128 + unit]) * bLds[192 + unit];
      }
    p0 += __shfl_xor(p0, 16); p0 += __shfl_xor(p0, 32);
  }

  short8v h1B[8];
  #define T1S(t, S) { \
    f32x4 a[4] = {}; \
    PIPE(S, 2); \
    _Pragma("unroll") \
    for (int f = 0; f < 16; ++f) \
      a[f >> 2] = MM16(FRAG(S, f), xf[f & 3], a[f >> 2]); \
    cvt16(a[0], a[1], bLds + 256 + (t) * 64,      hi, h1B[2 * (t)]); \
    cvt16(a[2], a[3], bLds + 256 + (t) * 64 + 32, hi, h1B[2 * (t) + 1]); \
  }
  T1S(0, 3) T1S(1, 4) T1S(2, 5) T1S(3, 6)

  short8v h2B[4];
  #define T2S(s, S, BOFF) { \
    f32x4 u[2] = {}; \
    PIPE(S, 2); \
    _Pragma("unroll") \
    for (int f = 0; f < 16; ++f) \
      u[f >> 3] = MM16(FRAG(S, f), h1B[f & 7], u[f >> 3]); \
    cvt16(u[0], u[1], bLds + 512 + (BOFF) + 32 * (s), hi, h2B[s]); \
  }

  f32x4 wacc[8] = {};
  #define T3S(s, S, NW) { \
    PIPE(S, NW); \
    _Pragma("unroll") \
    for (int f = 0; f < 16; ++f) \
      wacc[f >> 1] = MM16(FRAG(S, f), h2B[2 * (s) + (f & 1)], wacc[f >> 1]); \
  }

  T2S(0, 7, 0) T2S(1, 8, 0) T2S(2, 9, 0) T2S(3, 10, 0)
  T3S(0, 11, 2) T3S(1, 12, 2)
  T2S(0, 13, 128) T2S(1, 14, 128) T2S(2, 15, 128) T2S(3, 16, 128)
  T3S(0, 17, 2) T3S(1, 18, 0)

  if (hi == 0 && valid) {
    float v = gw * (p0 + sb3[e]);
    if (OUTMODE == 0) scoreP[slotbase + row] = v; else atomicAdd(&score_out[tok], v);
  }
  if (valid) {
    if (OUTMODE == 0) {
      unsigned short* dst = trajP + (size_t)(slotbase + row) * 120;
      #pragma unroll
      for (int t = 0; t < 8; ++t)
        #pragma unroll
        for (int r = 0; r < 4; r += 2) {
          int unit = t * 16 + 4 * hi + r;
          if (unit + 1 < 120) {
            float a0 = gw * (wacc[t][r] + bLds[768 + unit]);
            float a1 = gw * (wacc[t][r + 1] + bLds[768 + unit + 1]);
            *(unsigned int*)(dst + unit) = (unsigned)f2bf(a0) | ((unsigned)f2bf(a1) << 16);
          }
        }
    } else {
      float* dst = traj_out + (size_t)tok * 120;
      #pragma unroll
      for (int t = 0; t < 8; ++t)
        #pragma unroll
        for (int r = 0; r < 4; ++r) {
          int unit = t * 16 + 4 * hi + r;
          if (unit < 120) atomicAdd(&dst[unit], gw * (wacc[t][r] + bLds[768 + unit]));
        }
    }
  }
}

// ---------------- combine ----------------
__global__ __launch_bounds__(256) void combine_kernel(
    const int* __restrict__ pairIdx, const int* __restrict__ csum,
    const unsigned short* __restrict__ trajP, const float* __restrict__ scoreP,
    float* __restrict__ traj_out, float* __restrict__ score_out)
{
  int t = blockIdx.x * 256 + threadIdx.x;
  if (t >= N_TOK) return;
  int p0 = pairIdx[2 * t], p1 = pairIdx[2 * t + 1];
  int e0 = p0 / N_TOK, e1 = p1 / N_TOK;
  size_t s0 = (size_t)csum[e0] + (p0 - e0 * N_TOK);
  size_t s1 = (size_t)csum[e1] + (p1 - e1 * N_TOK);
  const unsigned short* r0 = trajP + s0 * 120;
  const unsigned short* r1 = trajP + s1 * 120;
  float* o = traj_out + (size_t)t * 120;
  #pragma unroll 6
  for (int i = 0; i < 30; ++i) {
    u16x4 a = *(const u16x4*)(r0 + i * 4);
    u16x4 b = *(const u16x4*)(r1 + i * 4);
    f32x4 v;
    #pragma unroll
    for (int jj = 0; jj < 4; ++jj) v[jj] = bf2f(a[jj]) + bf2f(b[jj]);
    *(f32x4*)(o + i * 4) = v;
  }
  score_out[t] = scoreP[s0] + scoreP[s1];
}

extern "C" void kernel_launch(void* const* d_in, const int* in_sizes, int n_in,
                              void* d_out, int out_size, void* d_ws, size_t ws_size,
                              hipStream_t stream) {
  (void)in_sizes; (void)n_in; (void)out_size;
  const float* x   = (const float*)d_in[0];
  const float* rW1 = (const float*)d_in[1];
  const float* rb1 = (const float*)d_in[2];
  const float* rW2 = (const float*)d_in[3];
  const float* rb2 = (const float*)d_in[4];
  const float* rW3 = (const float*)d_in[5];
  const float* rb3 = (const float*)d_in[6];
  const float* tW1 = (const float*)d_in[7];
  const float* tb1 = (const float*)d_in[8];
  const float* tW2 = (const float*)d_in[9];
  const float* tb2 = (const float*)d_in[10];
  const float* tW3 = (const float*)d_in[11];
  const float* tb3 = (const float*)d_in[12];
  const float* sW1 = (const float*)d_in[13];
  const float* sb1 = (const float*)d_in[14];
  const float* sW2 = (const float*)d_in[15];
  const float* sb2 = (const float*)d_in[16];
  const float* sW3 = (const float*)d_in[17];
  const float* sb3 = (const float*)d_in[18];
  float* out = (float*)d_out;

  // workspace carve (bytes)
  char* wsb = (char*)d_ws;
  int*   cnt     = (int*)(wsb + 0);
  float* probsum = (float*)(wsb + 32);
  int*   csum    = (int*)(wsb + 64);
  int*   pairTok = (int*)(wsb + 96);
  float* pairW   = (float*)(wsb + 96 + (size_t)6 * N_TOK * 4);
  int*   pairIdx = (int*)(wsb + 96 + (size_t)12 * N_TOK * 4);
  float* scoreP  = (float*)(wsb + 96 + (size_t)14 * N_TOK * 4);
  unsigned short* blob  = (unsigned short*)(wsb + 96 + (size_t)16 * N_TOK * 4);
  unsigned short* rblob = (unsigned short*)(wsb + 96 + (size_t)16 * N_TOK * 4 + (size_t)6 * PER_E * 2);
  unsigned short* trajP = (unsigned short*)(wsb + 96 + (size_t)16 * N_TOK * 4 + (size_t)6 * PER_E * 2
                                            + (size_t)RSTAGES * 8192 * 2);
  size_t need = 96 + (size_t)16 * N_TOK * 4 + (size_t)6 * PER_E * 2 + (size_t)RSTAGES * 8192 * 2
              + (size_t)2 * N_TOK * 120 * 2;
  bool scratch = ws_size >= need;

  hipMemsetAsync(wsb, 0, 96, stream);
  if (!scratch) hipMemsetAsync(d_out, 0, (size_t)(N_TOK * 121) * 4, stream);

  prep_weights<<<(6 * PER_E) / 256, 256, 0, stream>>>(tW1, tW2, tW3, sW1, sW2, blob);
  prep_router<<<(RSTAGES * 8192) / 256, 256, 0, stream>>>(rW1, rW2, rblob);
  router_mfma<<<N_TOK / 128, 512, 0, stream>>>(x, rblob, rb1, rb2, rW3, rb3,
                                               out + PROB_OFF, pairTok, pairW, pairIdx, cnt, probsum);
  aux_kernel<<<1, 64, 0, stream>>>(probsum, cnt, csum, out + AUX_OFF);
  if (scratch) {
    expert_kernel<0><<<dim3(N_TOK / 128, 6), 512, 0, stream>>>(
        x, blob, tb1, tb2, tb3, sb1, sb2, sW3, sb3, pairTok, pairW, cnt, csum,
        out + TRAJ_OFF, out + SCORE_OFF, trajP, scoreP);
    combine_kernel<<<N_TOK / 256, 256, 0, stream>>>(pairIdx, csum, trajP, scoreP,
                                                    out + TRAJ_OFF, out + SCORE_OFF);
  } else {
    expert_kernel<1><<<dim3(N_TOK / 128, 6), 512, 0, stream>>>(
        x, blob, tb1, tb2, tb3, sb1, sb2, sW3, sb3, pairTok, pairW, cnt, csum,
        out + TRAJ_OFF, out + SCORE_OFF, trajP, scoreP);
  }
}